// Round 7
// baseline (7185.500 us; speedup 1.0000x reference)
//
#include <hip/hip_runtime.h>

// Problem constants
#define BATCH   16
#define CH      64
#define HH      56
#define WW      56
#define NCENT   1024
#define KTOT    576      // C * 3 * 3 (GEMM K)
#define MTOT    50176    // B*H*W
#define MTILE   128
#define KC      16
#define NSPLIT  4        // each phase-1 block covers 256 centroids (2 ntiles of 128)
#define VDIM    128
#define TOPK    8
#define SPLITK  10       // fp32 candidates kept per split (margin 2 over 8)
#define CAND    12       // merged candidates re-accumulated canonically (margin 4)

typedef float f4 __attribute__((ext_vector_type(4)));

// ---------------------------------------------------------------------------
// K2: table[k][n][o] = sum_v conv_w[o, k*128+v] * values[n, v]
// grid = 8 * 64 blocks (k, n-chunk of 16), 256 threads
// ---------------------------------------------------------------------------
__global__ __launch_bounds__(256) void k_table(const float* __restrict__ values,
                                               const float* __restrict__ conv_w,
                                               float* __restrict__ table) {
    __shared__ float wk[128][132];   // conv_w slab for this k, padded
    __shared__ float vals[16][128];  // 16 value rows

    const int t = threadIdx.x;
    const int k = blockIdx.x >> 6;          // 0..7
    const int n0 = (blockIdx.x & 63) * 16;  // 0..1008

    {
        const int row = t >> 1;
        const int seg = (t & 1) * 64;
        const f4* src = (const f4*)(conv_w + row * 1024 + k * 128 + seg);
#pragma unroll
        for (int q = 0; q < 16; ++q) *(f4*)&wk[row][seg + q * 4] = src[q];
    }
    {
        const int r = t >> 4;
        const int col = (t & 15) * 8;
        const f4* src = (const f4*)(values + (n0 + r) * VDIM + col);
        *(f4*)&vals[r][col] = src[0];
        *(f4*)&vals[r][col + 4] = src[1];
    }
    __syncthreads();

    const int o = t & 127;
    const int ngrp = t >> 7;  // 0..1
    float acc[8];
#pragma unroll
    for (int r = 0; r < 8; ++r) acc[r] = 0.f;

    for (int v = 0; v < 128; ++v) {
        const float w = wk[o][v];
#pragma unroll
        for (int r = 0; r < 8; ++r)
            acc[r] = fmaf(w, vals[ngrp * 8 + r][v], acc[r]);
    }
#pragma unroll
    for (int r = 0; r < 8; ++r) {
        const int n = n0 + ngrp * 8 + r;
        table[(((k << 10) + n) << 7) + o] = acc[r];
    }
}

// ---------------------------------------------------------------------------
// K1: fused dist GEMM (fp32, any order — candidate generation only) +
// per-row top-10 over a 256-wide centroid split.
// grid = 392 m-tiles * 4 splits = 1568 blocks, 256 threads
// ---------------------------------------------------------------------------
__global__ __launch_bounds__(256, 3) void k_dist_topk(const float* __restrict__ x,
                                                      const float* __restrict__ kern,
                                                      const float* __restrict__ bias,
                                                      float* __restrict__ dws,
                                                      int* __restrict__ iws) {
    __shared__ float A_lds[KC][MTILE];
    __shared__ float B_lds[KC][128];
    __shared__ float dist_lds[MTILE][65];  // pad 65 -> conflict-free row scans

    const int t = threadIdx.x;
    const int bm = blockIdx.x >> 2;
    const int split = blockIdx.x & 3;
    const int m0 = bm * MTILE;

    const int tx = t & 15;
    const int ty = t >> 4;
    const int ty4 = ty * 4;
    const int tx4 = tx * 4;

    // A loader: fixed location per thread
    const int ml = t & 127;
    const int L = m0 + ml;
    const int b = L / 3136;
    const int hw = L - b * 3136;
    const int hh = hw / 56;
    const int wp = hw - hh * 56;
    const float* xb = x + b * (CH * 3136);
    const int kbase = (t >> 7) * 8;  // 0 or 8

    // B loader
    const int nl = t >> 1;           // 0..127
    const int khalf = (t & 1) * 8;   // 0 or 8

    float top_d[SPLITK];
    int top_i[SPLITK];
#pragma unroll
    for (int j = 0; j < SPLITK; ++j) { top_d[j] = 3.0e38f; top_i[j] = 0; }

    for (int nt = 0; nt < 2; ++nt) {
        const int n0 = split * 256 + nt * 128;
        const float* Bk = kern + (n0 + nl) * KTOT + khalf;

        float acc[2][2][4][4];
#pragma unroll
        for (int a0 = 0; a0 < 2; ++a0)
#pragma unroll
            for (int a1 = 0; a1 < 2; ++a1)
#pragma unroll
                for (int i = 0; i < 4; ++i)
#pragma unroll
                    for (int j = 0; j < 4; ++j) acc[a0][a1][i][j] = 0.f;

#pragma unroll 1
        for (int chunk = 0; chunk < KTOT / KC; ++chunk) {
            __syncthreads();  // previous tile reads done
            // stage A (8 elems/thread, im2col on the fly)
#pragma unroll
            for (int j = 0; j < 8; ++j) {
                const int kg = chunk * KC + kbase + j;  // wave-uniform
                const int c = kg / 9;
                const int tap = kg - c * 9;
                const int dh = tap / 3;
                const int dw = tap - dh * 3;
                const int hy = hh + dh - 1;
                const int wx = wp + dw - 1;
                float v = 0.f;
                if ((unsigned)hy < 56u && (unsigned)wx < 56u)
                    v = xb[c * 3136 + hy * 56 + wx];
                A_lds[kbase + j][ml] = v;
            }
            // stage B (2 f4/thread)
            {
                const f4* src = (const f4*)(Bk + chunk * KC);
                const f4 b0 = src[0], b1 = src[1];
                B_lds[khalf + 0][nl] = b0[0];
                B_lds[khalf + 1][nl] = b0[1];
                B_lds[khalf + 2][nl] = b0[2];
                B_lds[khalf + 3][nl] = b0[3];
                B_lds[khalf + 4][nl] = b1[0];
                B_lds[khalf + 5][nl] = b1[1];
                B_lds[khalf + 6][nl] = b1[2];
                B_lds[khalf + 7][nl] = b1[3];
            }
            __syncthreads();
#pragma unroll
            for (int kkl = 0; kkl < KC; ++kkl) {
                const f4 a0 = *(const f4*)&A_lds[kkl][ty4];
                const f4 a1 = *(const f4*)&A_lds[kkl][ty4 + 64];
                const f4 bb0 = *(const f4*)&B_lds[kkl][tx4];
                const f4 bb1 = *(const f4*)&B_lds[kkl][tx4 + 64];
#pragma unroll
                for (int i = 0; i < 4; ++i)
#pragma unroll
                    for (int j = 0; j < 4; ++j) {
                        acc[0][0][i][j] = fmaf(a0[i], bb0[j], acc[0][0][i][j]);
                        acc[0][1][i][j] = fmaf(a0[i], bb1[j], acc[0][1][i][j]);
                        acc[1][0][i][j] = fmaf(a1[i], bb0[j], acc[1][0][i][j]);
                        acc[1][1][i][j] = fmaf(a1[i], bb1[j], acc[1][1][i][j]);
                    }
            }
        }

        // bias + stage dist + per-row top-10 merge, two 64-col halves
#pragma unroll 1
        for (int hc = 0; hc < 2; ++hc) {
            __syncthreads();  // previous scan done / GEMM reads done
            const f4 bv = *(const f4*)&bias[n0 + hc * 64 + tx4];
#pragma unroll
            for (int ih = 0; ih < 2; ++ih)
#pragma unroll
                for (int i = 0; i < 4; ++i)
#pragma unroll
                    for (int j = 0; j < 4; ++j)
                        dist_lds[ih * 64 + ty4 + i][tx4 + j] = acc[ih][hc][i][j] + bv[j];
            __syncthreads();
            if (t < 128) {
                const int r = t;
                const int nbase = n0 + hc * 64;
                float tlast = top_d[SPLITK - 1];
#pragma unroll 8
                for (int c = 0; c < 64; ++c) {
                    const float v = dist_lds[r][c];
                    if (v < tlast) {
                        top_d[SPLITK - 1] = v;
                        top_i[SPLITK - 1] = nbase + c;
#pragma unroll
                        for (int j = SPLITK - 1; j >= 1; --j) {
                            if (top_d[j] < top_d[j - 1]) {
                                const float td = top_d[j]; top_d[j] = top_d[j - 1]; top_d[j - 1] = td;
                                const int tii = top_i[j]; top_i[j] = top_i[j - 1]; top_i[j - 1] = tii;
                            }
                        }
                        tlast = top_d[SPLITK - 1];
                    }
                }
            }
        }
    }

    if (t < 128) {
#pragma unroll
        for (int j = 0; j < SPLITK; ++j) {
            dws[(split * SPLITK + j) * MTOT + m0 + t] = top_d[j];
            iws[(split * SPLITK + j) * MTOT + m0 + t] = top_i[j];
        }
    }
}

// ---------------------------------------------------------------------------
// K3: merge 4x10 candidates -> top-12, re-accumulate each candidate's dist
// with the XLA-CPU/Eigen NHWC chain: single fp32 accumulator, fmaf, order
// k' = (dh,dw,c) with c INNERMOST (tap-major) — the order Eigen's
// SpatialConvolution (NCHW canonicalized to NHWC) sums in. Then one fp32
// add of bias. Stable top-8 by (fp32 value, index). Gather, write out.
// grid = MTOT/64 = 784 blocks, 256 threads.
// ---------------------------------------------------------------------------
__global__ __launch_bounds__(256) void k_refine_out(const float* __restrict__ x,
                                                    const float* __restrict__ kern,
                                                    const float* __restrict__ bias,
                                                    const float* __restrict__ dws,
                                                    const int* __restrict__ iws,
                                                    const float* __restrict__ table,
                                                    const float* __restrict__ conv_b,
                                                    float* __restrict__ out) {
    __shared__ float  A_lds[KC][64];
    __shared__ int    id_lds[64][CAND];
    __shared__ float  dd_lds[64][CAND];
    __shared__ int    id8[64][TOPK];

    const int t = threadIdx.x;
    const int ll = t & 63;
    const int qs = t >> 6;  // 0..3
    const int l0 = blockIdx.x * 64;
    const int loc = l0 + ll;
    const int b = l0 / 3136;  // uniform per block (64 | 3136)
    const int hw = loc - b * 3136;
    const int hh = hw / 56;
    const int wp = hw - hh * 56;
    const float* xb = x + b * (CH * 3136);

    // 1) merge 4 split-lists (fp32) -> top-12 candidate ids
    if (t < 64) {
        float td[CAND];
        int ti[CAND];
#pragma unroll
        for (int j = 0; j < CAND; ++j) { td[j] = 3.0e38f; ti[j] = 0; }
#pragma unroll
        for (int s = 0; s < NSPLIT; ++s)
#pragma unroll
            for (int j = 0; j < SPLITK; ++j) {
                const float v = dws[(s * SPLITK + j) * MTOT + loc];
                const int ii = iws[(s * SPLITK + j) * MTOT + loc];
                if (v < td[CAND - 1]) {
                    td[CAND - 1] = v; ti[CAND - 1] = ii;
#pragma unroll
                    for (int q = CAND - 1; q >= 1; --q) {
                        if (td[q] < td[q - 1]) {
                            const float a = td[q]; td[q] = td[q - 1]; td[q - 1] = a;
                            const int bq = ti[q]; ti[q] = ti[q - 1]; ti[q - 1] = bq;
                        }
                    }
                }
            }
#pragma unroll
        for (int j = 0; j < CAND; ++j) id_lds[t][j] = ti[j];
    }
    __syncthreads();

    // 2) canonical fp32 re-accumulation, tap-major / channel-innermost chain:
    //    for dh: for dw: for c: acc = fmaf(x[c, h+dh-1, w+dw-1], w[n,c,dh,dw], acc)
    //    thread (ll,qs) does candidates 3qs..3qs+2.
    const int s0 = qs * 3;
    const int c0i = id_lds[ll][s0 + 0];
    const int c1i = id_lds[ll][s0 + 1];
    const int c2i = id_lds[ll][s0 + 2];
    const float* Kr0 = kern + c0i * KTOT;
    const float* Kr1 = kern + c1i * KTOT;
    const float* Kr2 = kern + c2i * KTOT;
    float a0 = 0.f, a1 = 0.f, a2 = 0.f;   // single accumulator each

    // 36 chunks: chunk cc covers tap = cc>>2, channels c0..c0+15 = (cc&3)*16..
#pragma unroll 1
    for (int cc = 0; cc < 36; ++cc) {
        const int tap = cc >> 2;
        const int c0 = (cc & 3) * 16;
        const int dh = tap / 3;
        const int dw = tap - dh * 3;
        const int hy = hh + dh - 1;
        const int wx = wp + dw - 1;
        const bool inb = ((unsigned)hy < 56u && (unsigned)wx < 56u);

        __syncthreads();  // previous chunk reads done
        // stage 16 channels of this tap for all 64 locations (kk = qs + 4q)
#pragma unroll
        for (int q = 0; q < 4; ++q) {
            const int kk = qs + 4 * q;
            float v = 0.f;
            if (inb) v = xb[(c0 + kk) * 3136 + hy * 56 + wx];
            A_lds[kk][ll] = v;
        }
        __syncthreads();
        // strictly ascending (tap, c) dependent fmaf chain per candidate
#pragma unroll
        for (int kk = 0; kk < KC; ++kk) {
            const float av = A_lds[kk][ll];
            const int koff = (c0 + kk) * 9 + tap;   // kern is (n, c, dh, dw)
            a0 = fmaf(av, Kr0[koff], a0);
            a1 = fmaf(av, Kr1[koff], a1);
            a2 = fmaf(av, Kr2[koff], a2);
        }
    }
    dd_lds[ll][s0 + 0] = a0 + bias[c0i];   // plain fp32 add, like dist + bias
    dd_lds[ll][s0 + 1] = a1 + bias[c1i];
    dd_lds[ll][s0 + 2] = a2 + bias[c2i];
    __syncthreads();

    // 3) stable top-8 of 12 by (fp32 value, index) = lax.top_k semantics
    if (t < 64) {
        float td[TOPK];
        int ti[TOPK];
#pragma unroll
        for (int j = 0; j < TOPK; ++j) { td[j] = 3.0e38f; ti[j] = 0x7fffffff; }
#pragma unroll
        for (int j = 0; j < CAND; ++j) {
            const float v = dd_lds[t][j];
            const int ii = id_lds[t][j];
            if (v < td[TOPK - 1] || (v == td[TOPK - 1] && ii < ti[TOPK - 1])) {
                td[TOPK - 1] = v; ti[TOPK - 1] = ii;
#pragma unroll
                for (int q = TOPK - 1; q >= 1; --q) {
                    if (td[q] < td[q - 1] || (td[q] == td[q - 1] && ti[q] < ti[q - 1])) {
                        const float a = td[q]; td[q] = td[q - 1]; td[q - 1] = a;
                        const int bq = ti[q]; ti[q] = ti[q - 1]; ti[q - 1] = bq;
                    }
                }
            }
        }
#pragma unroll
        for (int j = 0; j < TOPK; ++j) id8[t][j] = ti[j];
    }
    __syncthreads();

    // 4) output: thread (ll,qs) handles o-channels qs*32..qs*32+31
    const int o0 = qs * 32;
    int idx[TOPK];
#pragma unroll
    for (int j = 0; j < TOPK; ++j) idx[j] = id8[ll][j];

    f4 acc[8];
#pragma unroll
    for (int q = 0; q < 8; ++q) acc[q] = *(const f4*)&conv_b[o0 + q * 4];
#pragma unroll
    for (int k = 0; k < TOPK; ++k) {
        const float* row = table + (((k << 10) + idx[k]) << 7) + o0;
#pragma unroll
        for (int q = 0; q < 8; ++q) {
            const f4 rv = *(const f4*)&row[q * 4];
            acc[q] += rv;
        }
    }
    float* ob = out + b * (VDIM * 3136) + hw;
#pragma unroll
    for (int q = 0; q < 8; ++q)
#pragma unroll
        for (int e = 0; e < 4; ++e)
            ob[(o0 + q * 4 + e) * 3136] = acc[q][e];
}

// ---------------------------------------------------------------------------
// ws layout (floats): table 1048576 | dws 2007040 | iws 2007040  (~20.3 MB)
// ---------------------------------------------------------------------------
extern "C" void kernel_launch(void* const* d_in, const int* in_sizes, int n_in,
                              void* d_out, int out_size, void* d_ws, size_t ws_size,
                              hipStream_t stream) {
    const float* x      = (const float*)d_in[0];
    const float* kern   = (const float*)d_in[1];  // already -centroids
    const float* bias   = (const float*)d_in[2];
    const float* values = (const float*)d_in[3];
    const float* conv_w = (const float*)d_in[4];
    const float* conv_b = (const float*)d_in[5];
    float* out = (float*)d_out;

    float* table = (float*)d_ws;                       // 8*1024*128
    float* dws = table + 8 * 1024 * VDIM;              // 4*10*50176
    int* iws = (int*)(dws + NSPLIT * SPLITK * MTOT);   // 4*10*50176

    k_table<<<dim3(8 * 64), dim3(256), 0, stream>>>(values, conv_w, table);
    k_dist_topk<<<dim3((MTOT / MTILE) * NSPLIT), dim3(256), 0, stream>>>(x, kern, bias, dws, iws);
    k_refine_out<<<dim3(MTOT / 64), dim3(256), 0, stream>>>(x, kern, bias, dws, iws, table, conv_b, out);
}

// Round 8
// 3749.773 us; speedup vs baseline: 1.9162x; 1.9162x over previous
//
#include <hip/hip_runtime.h>

// Problem constants
#define BATCH   16
#define CH      64
#define HH      56
#define WW      56
#define NCENT   1024
#define KTOT    576      // C * 3 * 3 (GEMM K)
#define MTOT    50176    // B*H*W
#define MTILE   128
#define KC      16
#define NSPLIT  4        // each phase-1 block covers 256 centroids (2 ntiles of 128)
#define VDIM    128
#define TOPK    8
#define SPLITK  10       // fp32 candidates kept per split (margin 2 over 8)
#define CAND    12       // merged candidates re-accumulated canonically (margin 4)

typedef float f4 __attribute__((ext_vector_type(4)));

// ---------------------------------------------------------------------------
// K2: table[k][n][o] = sum_v conv_w[o, k*128+v] * values[n, v]
// grid = 8 * 64 blocks (k, n-chunk of 16), 256 threads
// ---------------------------------------------------------------------------
__global__ __launch_bounds__(256) void k_table(const float* __restrict__ values,
                                               const float* __restrict__ conv_w,
                                               float* __restrict__ table) {
    __shared__ float wk[128][132];   // conv_w slab for this k, padded
    __shared__ float vals[16][128];  // 16 value rows

    const int t = threadIdx.x;
    const int k = blockIdx.x >> 6;          // 0..7
    const int n0 = (blockIdx.x & 63) * 16;  // 0..1008

    {
        const int row = t >> 1;
        const int seg = (t & 1) * 64;
        const f4* src = (const f4*)(conv_w + row * 1024 + k * 128 + seg);
#pragma unroll
        for (int q = 0; q < 16; ++q) *(f4*)&wk[row][seg + q * 4] = src[q];
    }
    {
        const int r = t >> 4;
        const int col = (t & 15) * 8;
        const f4* src = (const f4*)(values + (n0 + r) * VDIM + col);
        *(f4*)&vals[r][col] = src[0];
        *(f4*)&vals[r][col + 4] = src[1];
    }
    __syncthreads();

    const int o = t & 127;
    const int ngrp = t >> 7;  // 0..1
    float acc[8];
#pragma unroll
    for (int r = 0; r < 8; ++r) acc[r] = 0.f;

    for (int v = 0; v < 128; ++v) {
        const float w = wk[o][v];
#pragma unroll
        for (int r = 0; r < 8; ++r)
            acc[r] = fmaf(w, vals[ngrp * 8 + r][v], acc[r]);
    }
#pragma unroll
    for (int r = 0; r < 8; ++r) {
        const int n = n0 + ngrp * 8 + r;
        table[(((k << 10) + n) << 7) + o] = acc[r];
    }
}

// ---------------------------------------------------------------------------
// K1: fused dist GEMM (fp32, any order — candidate generation only) +
// per-row top-10 over a 256-wide centroid split.
// grid = 392 m-tiles * 4 splits = 1568 blocks, 256 threads
// NOTE: every index into acc[][][][] must be compile-time constant — a
// runtime index demotes the accumulator to scratch (R7: 26 GB HBM traffic,
// VALUBusy 10%). The epilogue hc loop is therefore fully unrolled.
// ---------------------------------------------------------------------------
__global__ __launch_bounds__(256, 3) void k_dist_topk(const float* __restrict__ x,
                                                      const float* __restrict__ kern,
                                                      const float* __restrict__ bias,
                                                      float* __restrict__ dws,
                                                      int* __restrict__ iws) {
    __shared__ float A_lds[KC][MTILE];
    __shared__ float B_lds[KC][128];
    __shared__ float dist_lds[MTILE][65];  // pad 65 -> conflict-free row scans

    const int t = threadIdx.x;
    const int bm = blockIdx.x >> 2;
    const int split = blockIdx.x & 3;
    const int m0 = bm * MTILE;

    const int tx = t & 15;
    const int ty = t >> 4;
    const int ty4 = ty * 4;
    const int tx4 = tx * 4;

    // A loader: fixed location per thread
    const int ml = t & 127;
    const int L = m0 + ml;
    const int b = L / 3136;
    const int hw = L - b * 3136;
    const int hh = hw / 56;
    const int wp = hw - hh * 56;
    const float* xb = x + b * (CH * 3136);
    const int kbase = (t >> 7) * 8;  // 0 or 8

    // B loader
    const int nl = t >> 1;           // 0..127
    const int khalf = (t & 1) * 8;   // 0 or 8

    float top_d[SPLITK];
    int top_i[SPLITK];
#pragma unroll
    for (int j = 0; j < SPLITK; ++j) { top_d[j] = 3.0e38f; top_i[j] = 0; }

    for (int nt = 0; nt < 2; ++nt) {
        const int n0 = split * 256 + nt * 128;
        const float* Bk = kern + (n0 + nl) * KTOT + khalf;

        float acc[2][2][4][4];
#pragma unroll
        for (int a0 = 0; a0 < 2; ++a0)
#pragma unroll
            for (int a1 = 0; a1 < 2; ++a1)
#pragma unroll
                for (int i = 0; i < 4; ++i)
#pragma unroll
                    for (int j = 0; j < 4; ++j) acc[a0][a1][i][j] = 0.f;

#pragma unroll 1
        for (int chunk = 0; chunk < KTOT / KC; ++chunk) {
            __syncthreads();  // previous tile reads done
            // stage A (8 elems/thread, im2col on the fly)
#pragma unroll
            for (int j = 0; j < 8; ++j) {
                const int kg = chunk * KC + kbase + j;  // wave-uniform
                const int c = kg / 9;
                const int tap = kg - c * 9;
                const int dh = tap / 3;
                const int dw = tap - dh * 3;
                const int hy = hh + dh - 1;
                const int wx = wp + dw - 1;
                float v = 0.f;
                if ((unsigned)hy < 56u && (unsigned)wx < 56u)
                    v = xb[c * 3136 + hy * 56 + wx];
                A_lds[kbase + j][ml] = v;
            }
            // stage B (2 f4/thread)
            {
                const f4* src = (const f4*)(Bk + chunk * KC);
                const f4 b0 = src[0], b1 = src[1];
                B_lds[khalf + 0][nl] = b0[0];
                B_lds[khalf + 1][nl] = b0[1];
                B_lds[khalf + 2][nl] = b0[2];
                B_lds[khalf + 3][nl] = b0[3];
                B_lds[khalf + 4][nl] = b1[0];
                B_lds[khalf + 5][nl] = b1[1];
                B_lds[khalf + 6][nl] = b1[2];
                B_lds[khalf + 7][nl] = b1[3];
            }
            __syncthreads();
#pragma unroll
            for (int kkl = 0; kkl < KC; ++kkl) {
                const f4 a0 = *(const f4*)&A_lds[kkl][ty4];
                const f4 a1 = *(const f4*)&A_lds[kkl][ty4 + 64];
                const f4 bb0 = *(const f4*)&B_lds[kkl][tx4];
                const f4 bb1 = *(const f4*)&B_lds[kkl][tx4 + 64];
#pragma unroll
                for (int i = 0; i < 4; ++i)
#pragma unroll
                    for (int j = 0; j < 4; ++j) {
                        acc[0][0][i][j] = fmaf(a0[i], bb0[j], acc[0][0][i][j]);
                        acc[0][1][i][j] = fmaf(a0[i], bb1[j], acc[0][1][i][j]);
                        acc[1][0][i][j] = fmaf(a1[i], bb0[j], acc[1][0][i][j]);
                        acc[1][1][i][j] = fmaf(a1[i], bb1[j], acc[1][1][i][j]);
                    }
            }
        }

        // bias + stage dist + per-row top-10 merge, two 64-col halves.
        // hc FULLY UNROLLED so acc[][hc][][] stays constant-indexed (VGPRs).
#pragma unroll
        for (int hc = 0; hc < 2; ++hc) {
            __syncthreads();  // previous scan done / GEMM reads done
            const f4 bv = *(const f4*)&bias[n0 + hc * 64 + tx4];
#pragma unroll
            for (int ih = 0; ih < 2; ++ih)
#pragma unroll
                for (int i = 0; i < 4; ++i)
#pragma unroll
                    for (int j = 0; j < 4; ++j)
                        dist_lds[ih * 64 + ty4 + i][tx4 + j] = acc[ih][hc][i][j] + bv[j];
            __syncthreads();
            if (t < 128) {
                const int r = t;
                const int nbase = n0 + hc * 64;
                float tlast = top_d[SPLITK - 1];
#pragma unroll 8
                for (int c = 0; c < 64; ++c) {
                    const float v = dist_lds[r][c];
                    if (v < tlast) {
                        top_d[SPLITK - 1] = v;
                        top_i[SPLITK - 1] = nbase + c;
#pragma unroll
                        for (int j = SPLITK - 1; j >= 1; --j) {
                            if (top_d[j] < top_d[j - 1]) {
                                const float td = top_d[j]; top_d[j] = top_d[j - 1]; top_d[j - 1] = td;
                                const int tii = top_i[j]; top_i[j] = top_i[j - 1]; top_i[j - 1] = tii;
                            }
                        }
                        tlast = top_d[SPLITK - 1];
                    }
                }
            }
        }
    }

    if (t < 128) {
#pragma unroll
        for (int j = 0; j < SPLITK; ++j) {
            dws[(split * SPLITK + j) * MTOT + m0 + t] = top_d[j];
            iws[(split * SPLITK + j) * MTOT + m0 + t] = top_i[j];
        }
    }
}

// ---------------------------------------------------------------------------
// K3: merge 4x10 candidates -> top-12, re-accumulate each candidate's dist
// with the XLA-CPU/Eigen NHWC chain: single fp32 accumulator, fmaf, order
// k' = (dh,dw,c) with c INNERMOST (tap-major). Then one fp32 add of bias.
// Stable top-8 by (fp32 value, index). Gather, write out.
// grid = MTOT/64 = 784 blocks, 256 threads.
// ---------------------------------------------------------------------------
__global__ __launch_bounds__(256) void k_refine_out(const float* __restrict__ x,
                                                    const float* __restrict__ kern,
                                                    const float* __restrict__ bias,
                                                    const float* __restrict__ dws,
                                                    const int* __restrict__ iws,
                                                    const float* __restrict__ table,
                                                    const float* __restrict__ conv_b,
                                                    float* __restrict__ out) {
    __shared__ float  A_lds[KC][64];
    __shared__ int    id_lds[64][CAND];
    __shared__ float  dd_lds[64][CAND];
    __shared__ int    id8[64][TOPK];

    const int t = threadIdx.x;
    const int ll = t & 63;
    const int qs = t >> 6;  // 0..3
    const int l0 = blockIdx.x * 64;
    const int loc = l0 + ll;
    const int b = l0 / 3136;  // uniform per block (64 | 3136)
    const int hw = loc - b * 3136;
    const int hh = hw / 56;
    const int wp = hw - hh * 56;
    const float* xb = x + b * (CH * 3136);

    // 1) merge 4 split-lists (fp32) -> top-12 candidate ids
    if (t < 64) {
        float td[CAND];
        int ti[CAND];
#pragma unroll
        for (int j = 0; j < CAND; ++j) { td[j] = 3.0e38f; ti[j] = 0; }
#pragma unroll
        for (int s = 0; s < NSPLIT; ++s)
#pragma unroll
            for (int j = 0; j < SPLITK; ++j) {
                const float v = dws[(s * SPLITK + j) * MTOT + loc];
                const int ii = iws[(s * SPLITK + j) * MTOT + loc];
                if (v < td[CAND - 1]) {
                    td[CAND - 1] = v; ti[CAND - 1] = ii;
#pragma unroll
                    for (int q = CAND - 1; q >= 1; --q) {
                        if (td[q] < td[q - 1]) {
                            const float a = td[q]; td[q] = td[q - 1]; td[q - 1] = a;
                            const int bq = ti[q]; ti[q] = ti[q - 1]; ti[q - 1] = bq;
                        }
                    }
                }
            }
#pragma unroll
        for (int j = 0; j < CAND; ++j) id_lds[t][j] = ti[j];
    }
    __syncthreads();

    // 2) canonical fp32 re-accumulation, tap-major / channel-innermost chain
    const int s0 = qs * 3;
    const int c0i = id_lds[ll][s0 + 0];
    const int c1i = id_lds[ll][s0 + 1];
    const int c2i = id_lds[ll][s0 + 2];
    const float* Kr0 = kern + c0i * KTOT;
    const float* Kr1 = kern + c1i * KTOT;
    const float* Kr2 = kern + c2i * KTOT;
    float a0 = 0.f, a1 = 0.f, a2 = 0.f;   // single accumulator each

    // 36 chunks: chunk cc covers tap = cc>>2, channels (cc&3)*16..+15
#pragma unroll 1
    for (int cc = 0; cc < 36; ++cc) {
        const int tap = cc >> 2;
        const int c0 = (cc & 3) * 16;
        const int dh = tap / 3;
        const int dw = tap - dh * 3;
        const int hy = hh + dh - 1;
        const int wx = wp + dw - 1;
        const bool inb = ((unsigned)hy < 56u && (unsigned)wx < 56u);

        __syncthreads();  // previous chunk reads done
#pragma unroll
        for (int q = 0; q < 4; ++q) {
            const int kk = qs + 4 * q;
            float v = 0.f;
            if (inb) v = xb[(c0 + kk) * 3136 + hy * 56 + wx];
            A_lds[kk][ll] = v;
        }
        __syncthreads();
#pragma unroll
        for (int kk = 0; kk < KC; ++kk) {
            const float av = A_lds[kk][ll];
            const int koff = (c0 + kk) * 9 + tap;   // kern is (n, c, dh, dw)
            a0 = fmaf(av, Kr0[koff], a0);
            a1 = fmaf(av, Kr1[koff], a1);
            a2 = fmaf(av, Kr2[koff], a2);
        }
    }
    dd_lds[ll][s0 + 0] = a0 + bias[c0i];   // plain fp32 add, like dist + bias
    dd_lds[ll][s0 + 1] = a1 + bias[c1i];
    dd_lds[ll][s0 + 2] = a2 + bias[c2i];
    __syncthreads();

    // 3) stable top-8 of 12 by (fp32 value, index) = lax.top_k semantics
    if (t < 64) {
        float td[TOPK];
        int ti[TOPK];
#pragma unroll
        for (int j = 0; j < TOPK; ++j) { td[j] = 3.0e38f; ti[j] = 0x7fffffff; }
#pragma unroll
        for (int j = 0; j < CAND; ++j) {
            const float v = dd_lds[t][j];
            const int ii = id_lds[t][j];
            if (v < td[TOPK - 1] || (v == td[TOPK - 1] && ii < ti[TOPK - 1])) {
                td[TOPK - 1] = v; ti[TOPK - 1] = ii;
#pragma unroll
                for (int q = TOPK - 1; q >= 1; --q) {
                    if (td[q] < td[q - 1] || (td[q] == td[q - 1] && ti[q] < ti[q - 1])) {
                        const float a = td[q]; td[q] = td[q - 1]; td[q - 1] = a;
                        const int bq = ti[q]; ti[q] = ti[q - 1]; ti[q - 1] = bq;
                    }
                }
            }
        }
#pragma unroll
        for (int j = 0; j < TOPK; ++j) id8[t][j] = ti[j];
    }
    __syncthreads();

    // 4) output: thread (ll,qs) handles o-channels qs*32..qs*32+31
    const int o0 = qs * 32;
    int idx[TOPK];
#pragma unroll
    for (int j = 0; j < TOPK; ++j) idx[j] = id8[ll][j];

    f4 acc[8];
#pragma unroll
    for (int q = 0; q < 8; ++q) acc[q] = *(const f4*)&conv_b[o0 + q * 4];
#pragma unroll
    for (int k = 0; k < TOPK; ++k) {
        const float* row = table + (((k << 10) + idx[k]) << 7) + o0;
#pragma unroll
        for (int q = 0; q < 8; ++q) {
            const f4 rv = *(const f4*)&row[q * 4];
            acc[q] += rv;
        }
    }
    float* ob = out + b * (VDIM * 3136) + hw;
#pragma unroll
    for (int q = 0; q < 8; ++q)
#pragma unroll
        for (int e = 0; e < 4; ++e)
            ob[(o0 + q * 4 + e) * 3136] = acc[q][e];
}

// ---------------------------------------------------------------------------
// ws layout (floats): table 1048576 | dws 2007040 | iws 2007040  (~20.3 MB)
// ---------------------------------------------------------------------------
extern "C" void kernel_launch(void* const* d_in, const int* in_sizes, int n_in,
                              void* d_out, int out_size, void* d_ws, size_t ws_size,
                              hipStream_t stream) {
    const float* x      = (const float*)d_in[0];
    const float* kern   = (const float*)d_in[1];  // already -centroids
    const float* bias   = (const float*)d_in[2];
    const float* values = (const float*)d_in[3];
    const float* conv_w = (const float*)d_in[4];
    const float* conv_b = (const float*)d_in[5];
    float* out = (float*)d_out;

    float* table = (float*)d_ws;                       // 8*1024*128
    float* dws = table + 8 * 1024 * VDIM;              // 4*10*50176
    int* iws = (int*)(dws + NSPLIT * SPLITK * MTOT);   // 4*10*50176

    k_table<<<dim3(8 * 64), dim3(256), 0, stream>>>(values, conv_w, table);
    k_dist_topk<<<dim3((MTOT / MTILE) * NSPLIT), dim3(256), 0, stream>>>(x, kern, bias, dws, iws);
    k_refine_out<<<dim3(MTOT / 64), dim3(256), 0, stream>>>(x, kern, bias, dws, iws, table, conv_b, out);
}

// Round 9
// 1910.816 us; speedup vs baseline: 3.7604x; 1.9624x over previous
//
#include <hip/hip_runtime.h>

// Problem constants
#define BATCH   16
#define CH      64
#define HH      56
#define WW      56
#define NCENT   1024
#define KTOT    576      // C * 3 * 3 (GEMM K)
#define MTOT    50176    // B*H*W
#define MTILE   128
#define KC      16
#define NSPLIT  4        // each phase-1 block covers 256 centroids (2 ntiles of 128)
#define VDIM    128
#define TOPK    8
#define SPLITK  10       // fp32 candidates kept per split (margin 2 over 8)
#define CAND    12       // merged candidates re-accumulated canonically (margin 4)

typedef float f4 __attribute__((ext_vector_type(4)));

// ---------------------------------------------------------------------------
// K2: table[k][n][o] = sum_v conv_w[o, k*128+v] * values[n, v]
// grid = 8 * 64 blocks (k, n-chunk of 16), 256 threads
// ---------------------------------------------------------------------------
__global__ __launch_bounds__(256) void k_table(const float* __restrict__ values,
                                               const float* __restrict__ conv_w,
                                               float* __restrict__ table) {
    __shared__ float wk[128][132];   // conv_w slab for this k, padded
    __shared__ float vals[16][128];  // 16 value rows

    const int t = threadIdx.x;
    const int k = blockIdx.x >> 6;          // 0..7
    const int n0 = (blockIdx.x & 63) * 16;  // 0..1008

    {
        const int row = t >> 1;
        const int seg = (t & 1) * 64;
        const f4* src = (const f4*)(conv_w + row * 1024 + k * 128 + seg);
#pragma unroll
        for (int q = 0; q < 16; ++q) *(f4*)&wk[row][seg + q * 4] = src[q];
    }
    {
        const int r = t >> 4;
        const int col = (t & 15) * 8;
        const f4* src = (const f4*)(values + (n0 + r) * VDIM + col);
        *(f4*)&vals[r][col] = src[0];
        *(f4*)&vals[r][col + 4] = src[1];
    }
    __syncthreads();

    const int o = t & 127;
    const int ngrp = t >> 7;  // 0..1
    float acc[8];
#pragma unroll
    for (int r = 0; r < 8; ++r) acc[r] = 0.f;

    for (int v = 0; v < 128; ++v) {
        const float w = wk[o][v];
#pragma unroll
        for (int r = 0; r < 8; ++r)
            acc[r] = fmaf(w, vals[ngrp * 8 + r][v], acc[r]);
    }
#pragma unroll
    for (int r = 0; r < 8; ++r) {
        const int n = n0 + ngrp * 8 + r;
        table[(((k << 10) + n) << 7) + o] = acc[r];
    }
}

// ---------------------------------------------------------------------------
// K1: fused dist GEMM (fp32, any order — candidate generation only) +
// per-row top-10 over a 256-wide centroid split.
// grid = 392 m-tiles * 4 splits = 1568 blocks, 256 threads.
// Register discipline (R7/R8 lessons):
//  - acc indices must be compile-time constant (runtime idx -> scratch).
//  - kkl unroll limited to 2: full unroll hoists ~64 ds_read_b128 worth of
//    live data, blowing the VGPR budget and spilling acc (R8: 2.4 GB scratch).
//  - dist_lds unioned with A/B staging: LDS 49.7->33.3 KB -> 4 blocks/CU.
// ---------------------------------------------------------------------------
__global__ __launch_bounds__(256, 4) void k_dist_topk(const float* __restrict__ x,
                                                      const float* __restrict__ kern,
                                                      const float* __restrict__ bias,
                                                      float* __restrict__ dws,
                                                      int* __restrict__ iws) {
    // union: [A_lds 8KB | B_lds 8KB] overlaid with dist_lds 33.3KB
    __shared__ char smem[MTILE * 65 * 4];
    float (*A_lds)[MTILE] = (float (*)[MTILE])smem;                  // [KC][128]
    float (*B_lds)[128]  = (float (*)[128])(smem + KC * MTILE * 4);  // [KC][128]
    float (*dist_lds)[65] = (float (*)[65])smem;                     // [128][65]

    const int t = threadIdx.x;
    const int bm = blockIdx.x >> 2;
    const int split = blockIdx.x & 3;
    const int m0 = bm * MTILE;

    const int tx = t & 15;
    const int ty = t >> 4;
    const int ty4 = ty * 4;
    const int tx4 = tx * 4;

    // A loader: fixed location per thread
    const int ml = t & 127;
    const int L = m0 + ml;
    const int b = L / 3136;
    const int hw = L - b * 3136;
    const int hh = hw / 56;
    const int wp = hw - hh * 56;
    const float* xb = x + b * (CH * 3136);
    const int kbase = (t >> 7) * 8;  // 0 or 8

    // B loader
    const int nl = t >> 1;           // 0..127
    const int khalf = (t & 1) * 8;   // 0 or 8

    float top_d[SPLITK];
    int top_i[SPLITK];
#pragma unroll
    for (int j = 0; j < SPLITK; ++j) { top_d[j] = 3.0e38f; top_i[j] = 0; }

    for (int nt = 0; nt < 2; ++nt) {
        const int n0 = split * 256 + nt * 128;
        const float* Bk = kern + (n0 + nl) * KTOT + khalf;

        float acc[2][2][4][4];
#pragma unroll
        for (int a0 = 0; a0 < 2; ++a0)
#pragma unroll
            for (int a1 = 0; a1 < 2; ++a1)
#pragma unroll
                for (int i = 0; i < 4; ++i)
#pragma unroll
                    for (int j = 0; j < 4; ++j) acc[a0][a1][i][j] = 0.f;

#pragma unroll 1
        for (int chunk = 0; chunk < KTOT / KC; ++chunk) {
            __syncthreads();  // previous tile reads (or aliased dist scan) done
            // stage A (8 elems/thread, im2col on the fly)
#pragma unroll
            for (int j = 0; j < 8; ++j) {
                const int kg = chunk * KC + kbase + j;  // wave-uniform
                const int c = kg / 9;
                const int tap = kg - c * 9;
                const int dh = tap / 3;
                const int dw = tap - dh * 3;
                const int hy = hh + dh - 1;
                const int wx = wp + dw - 1;
                float v = 0.f;
                if ((unsigned)hy < 56u && (unsigned)wx < 56u)
                    v = xb[c * 3136 + hy * 56 + wx];
                A_lds[kbase + j][ml] = v;
            }
            // stage B (2 f4/thread)
            {
                const f4* src = (const f4*)(Bk + chunk * KC);
                const f4 b0 = src[0], b1 = src[1];
                B_lds[khalf + 0][nl] = b0[0];
                B_lds[khalf + 1][nl] = b0[1];
                B_lds[khalf + 2][nl] = b0[2];
                B_lds[khalf + 3][nl] = b0[3];
                B_lds[khalf + 4][nl] = b1[0];
                B_lds[khalf + 5][nl] = b1[1];
                B_lds[khalf + 6][nl] = b1[2];
                B_lds[khalf + 7][nl] = b1[3];
            }
            __syncthreads();
            // unroll 2 ONLY: cap live loaded data so acc stays in VGPRs
#pragma unroll 2
            for (int kkl = 0; kkl < KC; ++kkl) {
                const f4 a0 = *(const f4*)&A_lds[kkl][ty4];
                const f4 a1 = *(const f4*)&A_lds[kkl][ty4 + 64];
                const f4 bb0 = *(const f4*)&B_lds[kkl][tx4];
                const f4 bb1 = *(const f4*)&B_lds[kkl][tx4 + 64];
#pragma unroll
                for (int i = 0; i < 4; ++i)
#pragma unroll
                    for (int j = 0; j < 4; ++j) {
                        acc[0][0][i][j] = fmaf(a0[i], bb0[j], acc[0][0][i][j]);
                        acc[0][1][i][j] = fmaf(a0[i], bb1[j], acc[0][1][i][j]);
                        acc[1][0][i][j] = fmaf(a1[i], bb0[j], acc[1][0][i][j]);
                        acc[1][1][i][j] = fmaf(a1[i], bb1[j], acc[1][1][i][j]);
                    }
            }
        }

        // bias + stage dist (aliases A/B — barriers separate phases) + scan.
        // hc FULLY UNROLLED so acc[][hc][][] stays constant-indexed (VGPRs).
#pragma unroll
        for (int hc = 0; hc < 2; ++hc) {
            __syncthreads();  // GEMM ds_reads / previous scan reads done
            const f4 bv = *(const f4*)&bias[n0 + hc * 64 + tx4];
#pragma unroll
            for (int ih = 0; ih < 2; ++ih)
#pragma unroll
                for (int i = 0; i < 4; ++i)
#pragma unroll
                    for (int j = 0; j < 4; ++j)
                        dist_lds[ih * 64 + ty4 + i][tx4 + j] = acc[ih][hc][i][j] + bv[j];
            __syncthreads();
            if (t < 128) {
                const int r = t;
                const int nbase = n0 + hc * 64;
                float tlast = top_d[SPLITK - 1];
#pragma unroll 8
                for (int c = 0; c < 64; ++c) {
                    const float v = dist_lds[r][c];
                    if (v < tlast) {
                        top_d[SPLITK - 1] = v;
                        top_i[SPLITK - 1] = nbase + c;
#pragma unroll
                        for (int j = SPLITK - 1; j >= 1; --j) {
                            if (top_d[j] < top_d[j - 1]) {
                                const float td = top_d[j]; top_d[j] = top_d[j - 1]; top_d[j - 1] = td;
                                const int tii = top_i[j]; top_i[j] = top_i[j - 1]; top_i[j - 1] = tii;
                            }
                        }
                        tlast = top_d[SPLITK - 1];
                    }
                }
            }
        }
    }

    if (t < 128) {
#pragma unroll
        for (int j = 0; j < SPLITK; ++j) {
            dws[(split * SPLITK + j) * MTOT + m0 + t] = top_d[j];
            iws[(split * SPLITK + j) * MTOT + m0 + t] = top_i[j];
        }
    }
}

// ---------------------------------------------------------------------------
// K3: merge 4x10 candidates -> top-12, re-accumulate each candidate's dist
// with the XLA-CPU/Eigen NHWC chain: single fp32 accumulator, fmaf, order
// k' = (dh,dw,c) with c INNERMOST (tap-major). Then one fp32 add of bias.
// Stable top-8 by (fp32 value, index). Gather, write out.
// grid = MTOT/64 = 784 blocks, 256 threads.
// ---------------------------------------------------------------------------
__global__ __launch_bounds__(256) void k_refine_out(const float* __restrict__ x,
                                                    const float* __restrict__ kern,
                                                    const float* __restrict__ bias,
                                                    const float* __restrict__ dws,
                                                    const int* __restrict__ iws,
                                                    const float* __restrict__ table,
                                                    const float* __restrict__ conv_b,
                                                    float* __restrict__ out) {
    __shared__ float  A_lds[KC][64];
    __shared__ int    id_lds[64][CAND];
    __shared__ float  dd_lds[64][CAND];
    __shared__ int    id8[64][TOPK];

    const int t = threadIdx.x;
    const int ll = t & 63;
    const int qs = t >> 6;  // 0..3
    const int l0 = blockIdx.x * 64;
    const int loc = l0 + ll;
    const int b = l0 / 3136;  // uniform per block (64 | 3136)
    const int hw = loc - b * 3136;
    const int hh = hw / 56;
    const int wp = hw - hh * 56;
    const float* xb = x + b * (CH * 3136);

    // 1) merge 4 split-lists (fp32) -> top-12 candidate ids
    if (t < 64) {
        float td[CAND];
        int ti[CAND];
#pragma unroll
        for (int j = 0; j < CAND; ++j) { td[j] = 3.0e38f; ti[j] = 0; }
#pragma unroll
        for (int s = 0; s < NSPLIT; ++s)
#pragma unroll
            for (int j = 0; j < SPLITK; ++j) {
                const float v = dws[(s * SPLITK + j) * MTOT + loc];
                const int ii = iws[(s * SPLITK + j) * MTOT + loc];
                if (v < td[CAND - 1]) {
                    td[CAND - 1] = v; ti[CAND - 1] = ii;
#pragma unroll
                    for (int q = CAND - 1; q >= 1; --q) {
                        if (td[q] < td[q - 1]) {
                            const float a = td[q]; td[q] = td[q - 1]; td[q - 1] = a;
                            const int bq = ti[q]; ti[q] = ti[q - 1]; ti[q - 1] = bq;
                        }
                    }
                }
            }
#pragma unroll
        for (int j = 0; j < CAND; ++j) id_lds[t][j] = ti[j];
    }
    __syncthreads();

    // 2) canonical fp32 re-accumulation, tap-major / channel-innermost chain
    const int s0 = qs * 3;
    const int c0i = id_lds[ll][s0 + 0];
    const int c1i = id_lds[ll][s0 + 1];
    const int c2i = id_lds[ll][s0 + 2];
    const float* Kr0 = kern + c0i * KTOT;
    const float* Kr1 = kern + c1i * KTOT;
    const float* Kr2 = kern + c2i * KTOT;
    float a0 = 0.f, a1 = 0.f, a2 = 0.f;   // single accumulator each

    // 36 chunks: chunk cc covers tap = cc>>2, channels (cc&3)*16..+15
#pragma unroll 1
    for (int cc = 0; cc < 36; ++cc) {
        const int tap = cc >> 2;
        const int c0 = (cc & 3) * 16;
        const int dh = tap / 3;
        const int dw = tap - dh * 3;
        const int hy = hh + dh - 1;
        const int wx = wp + dw - 1;
        const bool inb = ((unsigned)hy < 56u && (unsigned)wx < 56u);

        __syncthreads();  // previous chunk reads done
#pragma unroll
        for (int q = 0; q < 4; ++q) {
            const int kk = qs + 4 * q;
            float v = 0.f;
            if (inb) v = xb[(c0 + kk) * 3136 + hy * 56 + wx];
            A_lds[kk][ll] = v;
        }
        __syncthreads();
#pragma unroll
        for (int kk = 0; kk < KC; ++kk) {
            const float av = A_lds[kk][ll];
            const int koff = (c0 + kk) * 9 + tap;   // kern is (n, c, dh, dw)
            a0 = fmaf(av, Kr0[koff], a0);
            a1 = fmaf(av, Kr1[koff], a1);
            a2 = fmaf(av, Kr2[koff], a2);
        }
    }
    dd_lds[ll][s0 + 0] = a0 + bias[c0i];   // plain fp32 add, like dist + bias
    dd_lds[ll][s0 + 1] = a1 + bias[c1i];
    dd_lds[ll][s0 + 2] = a2 + bias[c2i];
    __syncthreads();

    // 3) stable top-8 of 12 by (fp32 value, index) = lax.top_k semantics
    if (t < 64) {
        float td[TOPK];
        int ti[TOPK];
#pragma unroll
        for (int j = 0; j < TOPK; ++j) { td[j] = 3.0e38f; ti[j] = 0x7fffffff; }
#pragma unroll
        for (int j = 0; j < CAND; ++j) {
            const float v = dd_lds[t][j];
            const int ii = id_lds[t][j];
            if (v < td[TOPK - 1] || (v == td[TOPK - 1] && ii < ti[TOPK - 1])) {
                td[TOPK - 1] = v; ti[TOPK - 1] = ii;
#pragma unroll
                for (int q = TOPK - 1; q >= 1; --q) {
                    if (td[q] < td[q - 1] || (td[q] == td[q - 1] && ti[q] < ti[q - 1])) {
                        const float a = td[q]; td[q] = td[q - 1]; td[q - 1] = a;
                        const int bq = ti[q]; ti[q] = ti[q - 1]; ti[q - 1] = bq;
                    }
                }
            }
        }
#pragma unroll
        for (int j = 0; j < TOPK; ++j) id8[t][j] = ti[j];
    }
    __syncthreads();

    // 4) output: thread (ll,qs) handles o-channels qs*32..qs*32+31
    const int o0 = qs * 32;
    int idx[TOPK];
#pragma unroll
    for (int j = 0; j < TOPK; ++j) idx[j] = id8[ll][j];

    f4 acc[8];
#pragma unroll
    for (int q = 0; q < 8; ++q) acc[q] = *(const f4*)&conv_b[o0 + q * 4];
#pragma unroll
    for (int k = 0; k < TOPK; ++k) {
        const float* row = table + (((k << 10) + idx[k]) << 7) + o0;
#pragma unroll
        for (int q = 0; q < 8; ++q) {
            const f4 rv = *(const f4*)&row[q * 4];
            acc[q] += rv;
        }
    }
    float* ob = out + b * (VDIM * 3136) + hw;
#pragma unroll
    for (int q = 0; q < 8; ++q)
#pragma unroll
        for (int e = 0; e < 4; ++e)
            ob[(o0 + q * 4 + e) * 3136] = acc[q][e];
}

// ---------------------------------------------------------------------------
// ws layout (floats): table 1048576 | dws 2007040 | iws 2007040  (~20.3 MB)
// ---------------------------------------------------------------------------
extern "C" void kernel_launch(void* const* d_in, const int* in_sizes, int n_in,
                              void* d_out, int out_size, void* d_ws, size_t ws_size,
                              hipStream_t stream) {
    const float* x      = (const float*)d_in[0];
    const float* kern   = (const float*)d_in[1];  // already -centroids
    const float* bias   = (const float*)d_in[2];
    const float* values = (const float*)d_in[3];
    const float* conv_w = (const float*)d_in[4];
    const float* conv_b = (const float*)d_in[5];
    float* out = (float*)d_out;

    float* table = (float*)d_ws;                       // 8*1024*128
    float* dws = table + 8 * 1024 * VDIM;              // 4*10*50176
    int* iws = (int*)(dws + NSPLIT * SPLITK * MTOT);   // 4*10*50176

    k_table<<<dim3(8 * 64), dim3(256), 0, stream>>>(values, conv_w, table);
    k_dist_topk<<<dim3((MTOT / MTILE) * NSPLIT), dim3(256), 0, stream>>>(x, kern, bias, dws, iws);
    k_refine_out<<<dim3(MTOT / 64), dim3(256), 0, stream>>>(x, kern, bias, dws, iws, table, conv_b, out);
}

// Round 10
// 1010.646 us; speedup vs baseline: 7.1098x; 1.8907x over previous
//
#include <hip/hip_runtime.h>

// Problem constants
#define BATCH   16
#define CH      64
#define HH      56
#define WW      56
#define NCENT   1024
#define KTOT    576      // C * 3 * 3 (GEMM K)
#define MTOT    50176    // B*H*W
#define MTILE   128
#define KC      16
#define NSPLIT  4
#define VDIM    128
#define TOPK    8

typedef float f4 __attribute__((ext_vector_type(4)));

// ---------------------------------------------------------------------------
// K0: rearrange kern (n, c, tap) -> kr (n, tap, c) so the GEMM can walk K in
// the reference's canonical accumulation order (tap-major, c-innermost) with
// contiguous staging loads. Reference semantics (proven R7): dist = single
// fp32 fmaf chain over k' = (dh, dw, c), then one fp32 add of bias.
// ---------------------------------------------------------------------------
__global__ __launch_bounds__(256) void k_rearrange(const float* __restrict__ kern,
                                                   float* __restrict__ kr) {
    const int o = blockIdx.x * 256 + threadIdx.x;  // 1024*576 = 2304 * 256
    const int c = o & 63;
    const int tap = (o >> 6) % 9;
    const int n = o / 576;
    kr[o] = kern[n * KTOT + c * 9 + tap];
}

// ---------------------------------------------------------------------------
// K2: table[k][n][o] = sum_v conv_w[o, k*128+v] * values[n, v]
// grid = 8 * 64 blocks (k, n-chunk of 16), 256 threads
// ---------------------------------------------------------------------------
__global__ __launch_bounds__(256) void k_table(const float* __restrict__ values,
                                               const float* __restrict__ conv_w,
                                               float* __restrict__ table) {
    __shared__ float wk[128][132];   // conv_w slab for this k, padded
    __shared__ float vals[16][128];  // 16 value rows

    const int t = threadIdx.x;
    const int k = blockIdx.x >> 6;          // 0..7
    const int n0 = (blockIdx.x & 63) * 16;  // 0..1008

    {
        const int row = t >> 1;
        const int seg = (t & 1) * 64;
        const f4* src = (const f4*)(conv_w + row * 1024 + k * 128 + seg);
#pragma unroll
        for (int q = 0; q < 16; ++q) *(f4*)&wk[row][seg + q * 4] = src[q];
    }
    {
        const int r = t >> 4;
        const int col = (t & 15) * 8;
        const f4* src = (const f4*)(values + (n0 + r) * VDIM + col);
        *(f4*)&vals[r][col] = src[0];
        *(f4*)&vals[r][col + 4] = src[1];
    }
    __syncthreads();

    const int o = t & 127;
    const int ngrp = t >> 7;  // 0..1
    float acc[8];
#pragma unroll
    for (int r = 0; r < 8; ++r) acc[r] = 0.f;

    for (int v = 0; v < 128; ++v) {
        const float w = wk[o][v];
#pragma unroll
        for (int r = 0; r < 8; ++r)
            acc[r] = fmaf(w, vals[ngrp * 8 + r][v], acc[r]);
    }
#pragma unroll
    for (int r = 0; r < 8; ++r) {
        const int n = n0 + ngrp * 8 + r;
        table[(((k << 10) + n) << 7) + o] = acc[r];
    }
}

// ---------------------------------------------------------------------------
// K1: fused dist GEMM + per-row top-8 over a 256-wide centroid split.
// Accumulation is BIT-EXACT to the reference: each acc[][]...[] is a single
// fp32 accumulator fed by fmaf in ascending (tap, c) order (chunks are
// tap-major, kkl walks c), then exactly one fp32 add of bias. Therefore the
// per-split top-8 values/indices are the reference's own — no refine needed.
// Register discipline (R7/R8): acc indices compile-time constant; kkl unroll
// capped at 2 (full unroll spills acc -> scratch); dist_lds unioned with A/B.
// grid = 392 m-tiles * 4 splits = 1568 blocks, 256 threads.
// ---------------------------------------------------------------------------
__global__ __launch_bounds__(256, 4) void k_dist_topk(const float* __restrict__ x,
                                                      const float* __restrict__ kr,
                                                      const float* __restrict__ bias,
                                                      float* __restrict__ dws,
                                                      int* __restrict__ iws) {
    // union: [A_lds 8KB | B_lds 8KB] overlaid with dist_lds 33.3KB
    __shared__ char smem[MTILE * 65 * 4];
    float (*A_lds)[MTILE] = (float (*)[MTILE])smem;                  // [KC][128]
    float (*B_lds)[128]  = (float (*)[128])(smem + KC * MTILE * 4);  // [KC][128]
    float (*dist_lds)[65] = (float (*)[65])smem;                     // [128][65]

    const int t = threadIdx.x;
    const int bm = blockIdx.x >> 2;
    const int split = blockIdx.x & 3;
    const int m0 = bm * MTILE;

    const int tx = t & 15;
    const int ty = t >> 4;
    const int ty4 = ty * 4;
    const int tx4 = tx * 4;

    // A loader: fixed location per thread
    const int ml = t & 127;
    const int L = m0 + ml;
    const int b = L / 3136;
    const int hw = L - b * 3136;
    const int hh = hw / 56;
    const int wp = hw - hh * 56;
    const float* xb = x + b * (CH * 3136);
    const int kbase = (t >> 7) * 8;  // 0 or 8

    // B loader
    const int nl = t >> 1;           // 0..127
    const int khalf = (t & 1) * 8;   // 0 or 8

    float top_d[TOPK];
    int top_i[TOPK];
#pragma unroll
    for (int j = 0; j < TOPK; ++j) { top_d[j] = 3.0e38f; top_i[j] = 0; }

    for (int nt = 0; nt < 2; ++nt) {
        const int n0 = split * 256 + nt * 128;
        const float* Bk = kr + (n0 + nl) * KTOT + khalf;

        float acc[2][2][4][4];
#pragma unroll
        for (int a0 = 0; a0 < 2; ++a0)
#pragma unroll
            for (int a1 = 0; a1 < 2; ++a1)
#pragma unroll
                for (int i = 0; i < 4; ++i)
#pragma unroll
                    for (int j = 0; j < 4; ++j) acc[a0][a1][i][j] = 0.f;

        // 36 chunks in canonical order: chunk cc -> tap = cc>>2 (dh,dw),
        // channels c = (cc&3)*16 + kkl. k' = tap*64 + c strictly ascending.
#pragma unroll 1
        for (int cc = 0; cc < 36; ++cc) {
            const int tap = cc >> 2;
            const int c0 = (cc & 3) * 16;
            const int dh = tap / 3;
            const int dw = tap - dh * 3;
            const int hy = hh + dh - 1;
            const int wx = wp + dw - 1;
            const bool inb = ((unsigned)hy < 56u && (unsigned)wx < 56u);
            const float* xp = xb + (c0 + kbase) * 3136 + hy * 56 + wx;

            __syncthreads();  // previous tile reads (or aliased dist scan) done
            // stage A: 8 channels at this tap (uniform predicate per chunk)
#pragma unroll
            for (int j = 0; j < 8; ++j) {
                float v = 0.f;
                if (inb) v = xp[j * 3136];
                A_lds[kbase + j][ml] = v;
            }
            // stage B (2 f4/thread, contiguous thanks to kr layout)
            {
                const f4* src = (const f4*)(Bk + cc * KC);
                const f4 b0 = src[0], b1 = src[1];
                B_lds[khalf + 0][nl] = b0[0];
                B_lds[khalf + 1][nl] = b0[1];
                B_lds[khalf + 2][nl] = b0[2];
                B_lds[khalf + 3][nl] = b0[3];
                B_lds[khalf + 4][nl] = b1[0];
                B_lds[khalf + 5][nl] = b1[1];
                B_lds[khalf + 6][nl] = b1[2];
                B_lds[khalf + 7][nl] = b1[3];
            }
            __syncthreads();
            // unroll 2 ONLY: cap live loaded data so acc stays in VGPRs
#pragma unroll 2
            for (int kkl = 0; kkl < KC; ++kkl) {
                const f4 a0 = *(const f4*)&A_lds[kkl][ty4];
                const f4 a1 = *(const f4*)&A_lds[kkl][ty4 + 64];
                const f4 bb0 = *(const f4*)&B_lds[kkl][tx4];
                const f4 bb1 = *(const f4*)&B_lds[kkl][tx4 + 64];
#pragma unroll
                for (int i = 0; i < 4; ++i)
#pragma unroll
                    for (int j = 0; j < 4; ++j) {
                        acc[0][0][i][j] = fmaf(a0[i], bb0[j], acc[0][0][i][j]);
                        acc[0][1][i][j] = fmaf(a0[i], bb1[j], acc[0][1][i][j]);
                        acc[1][0][i][j] = fmaf(a1[i], bb0[j], acc[1][0][i][j]);
                        acc[1][1][i][j] = fmaf(a1[i], bb1[j], acc[1][1][i][j]);
                    }
            }
        }

        // +bias (the reference's single fp32 add) + stage + per-row top-8.
        // hc FULLY UNROLLED so acc[][hc][][] stays constant-indexed (VGPRs).
#pragma unroll
        for (int hc = 0; hc < 2; ++hc) {
            __syncthreads();  // GEMM ds_reads / previous scan reads done
            const f4 bv = *(const f4*)&bias[n0 + hc * 64 + tx4];
#pragma unroll
            for (int ih = 0; ih < 2; ++ih)
#pragma unroll
                for (int i = 0; i < 4; ++i)
#pragma unroll
                    for (int j = 0; j < 4; ++j)
                        dist_lds[ih * 64 + ty4 + i][tx4 + j] = acc[ih][hc][i][j] + bv[j];
            __syncthreads();
            if (t < 128) {
                const int r = t;
                const int nbase = n0 + hc * 64;
                float tlast = top_d[TOPK - 1];
#pragma unroll 8
                for (int c = 0; c < 64; ++c) {
                    const float v = dist_lds[r][c];
                    if (v < tlast) {  // strict + ascending index = lax.top_k ties
                        top_d[TOPK - 1] = v;
                        top_i[TOPK - 1] = nbase + c;
#pragma unroll
                        for (int j = TOPK - 1; j >= 1; --j) {
                            if (top_d[j] < top_d[j - 1]) {
                                const float td = top_d[j]; top_d[j] = top_d[j - 1]; top_d[j - 1] = td;
                                const int tii = top_i[j]; top_i[j] = top_i[j - 1]; top_i[j - 1] = tii;
                            }
                        }
                        tlast = top_d[TOPK - 1];
                    }
                }
            }
        }
    }

    if (t < 128) {
#pragma unroll
        for (int j = 0; j < TOPK; ++j) {
            dws[(split * TOPK + j) * MTOT + m0 + t] = top_d[j];
            iws[(split * TOPK + j) * MTOT + m0 + t] = top_i[j];
        }
    }
}

// ---------------------------------------------------------------------------
// K3: merge 4 exact per-split top-8 lists by lex (fp32 value, index) ->
// global top-8 (= lax.top_k exactly, since values are the reference's own),
// gather table rows, write out. grid = MTOT/64 = 784 blocks, 256 threads.
// ---------------------------------------------------------------------------
__global__ __launch_bounds__(256) void k_merge_out(const float* __restrict__ dws,
                                                   const int* __restrict__ iws,
                                                   const float* __restrict__ table,
                                                   const float* __restrict__ conv_b,
                                                   float* __restrict__ out) {
    __shared__ int id8[64][TOPK];
    const int t = threadIdx.x;
    const int l0 = blockIdx.x * 64;
    const int b = l0 / 3136;  // uniform per block (64 | 3136)

    if (t < 64) {
        const int loc = l0 + t;
        float td[TOPK];
        int ti[TOPK];
#pragma unroll
        for (int j = 0; j < TOPK; ++j) { td[j] = 3.0e38f; ti[j] = 0x7fffffff; }
#pragma unroll
        for (int s = 0; s < NSPLIT; ++s)
#pragma unroll
            for (int j = 0; j < TOPK; ++j) {
                const float v = dws[(s * TOPK + j) * MTOT + loc];
                const int ii = iws[(s * TOPK + j) * MTOT + loc];
                if (v < td[TOPK - 1] || (v == td[TOPK - 1] && ii < ti[TOPK - 1])) {
                    td[TOPK - 1] = v; ti[TOPK - 1] = ii;
#pragma unroll
                    for (int q = TOPK - 1; q >= 1; --q) {
                        if (td[q] < td[q - 1] || (td[q] == td[q - 1] && ti[q] < ti[q - 1])) {
                            const float a = td[q]; td[q] = td[q - 1]; td[q - 1] = a;
                            const int bq = ti[q]; ti[q] = ti[q - 1]; ti[q - 1] = bq;
                        }
                    }
                }
            }
#pragma unroll
        for (int j = 0; j < TOPK; ++j) id8[t][j] = ti[j];
    }
    __syncthreads();

    // output: thread (ll = t&63, qs = t>>6) handles o-channels qs*32..+31
    const int ll = t & 63;
    const int qs = t >> 6;
    const int loc = l0 + ll;
    const int hw = loc - b * 3136;
    const int o0 = qs * 32;

    int idx[TOPK];
#pragma unroll
    for (int j = 0; j < TOPK; ++j) idx[j] = id8[ll][j];

    f4 acc[8];
#pragma unroll
    for (int q = 0; q < 8; ++q) acc[q] = *(const f4*)&conv_b[o0 + q * 4];
#pragma unroll
    for (int k = 0; k < TOPK; ++k) {
        const float* row = table + (((k << 10) + idx[k]) << 7) + o0;
#pragma unroll
        for (int q = 0; q < 8; ++q) {
            const f4 rv = *(const f4*)&row[q * 4];
            acc[q] += rv;
        }
    }
    float* ob = out + b * (VDIM * 3136) + hw;
#pragma unroll
    for (int q = 0; q < 8; ++q)
#pragma unroll
        for (int e = 0; e < 4; ++e)
            ob[(o0 + q * 4 + e) * 3136] = acc[q][e];
}

// ---------------------------------------------------------------------------
// ws layout (floats): kr 589824 | table 1048576 | dws 1605632 | iws 1605632
// total ~19.4 MB
// ---------------------------------------------------------------------------
extern "C" void kernel_launch(void* const* d_in, const int* in_sizes, int n_in,
                              void* d_out, int out_size, void* d_ws, size_t ws_size,
                              hipStream_t stream) {
    const float* x      = (const float*)d_in[0];
    const float* kern   = (const float*)d_in[1];  // already -centroids
    const float* bias   = (const float*)d_in[2];
    const float* values = (const float*)d_in[3];
    const float* conv_w = (const float*)d_in[4];
    const float* conv_b = (const float*)d_in[5];
    float* out = (float*)d_out;

    float* kr = (float*)d_ws;                         // 1024*576
    float* table = kr + NCENT * KTOT;                 // 8*1024*128
    float* dws = table + 8 * NCENT * VDIM;            // 4*8*50176
    int* iws = (int*)(dws + NSPLIT * TOPK * MTOT);    // 4*8*50176

    k_rearrange<<<dim3(NCENT * KTOT / 256), dim3(256), 0, stream>>>(kern, kr);
    k_table<<<dim3(8 * 64), dim3(256), 0, stream>>>(values, conv_w, table);
    k_dist_topk<<<dim3((MTOT / MTILE) * NSPLIT), dim3(256), 0, stream>>>(x, kr, bias, dws, iws);
    k_merge_out<<<dim3(MTOT / 64), dim3(256), 0, stream>>>(dws, iws, table, conv_b, out);
}

// Round 11
// 988.957 us; speedup vs baseline: 7.2657x; 1.0219x over previous
//
#include <hip/hip_runtime.h>

// Problem constants
#define BATCH   16
#define CH      64
#define NCENT   1024
#define KTOT    576      // 64 ch * 9 taps
#define MTOT    50176    // B*H*W
#define VDIM    128
#define TOPK    8
#define NSUB    4        // n sub-splits = waves (each covers 256 n, 64 per nt)
#define SK      10       // bf16 candidates kept per sub-split
#define POOL    16       // merged candidates refined canonically

typedef float f4 __attribute__((ext_vector_type(4)));
typedef short bf16x8 __attribute__((ext_vector_type(8)));
typedef int i4 __attribute__((ext_vector_type(4)));

__device__ __forceinline__ unsigned short f2bf(float f) {
    union { float f; unsigned u; } c; c.f = f;
    return (unsigned short)((c.u + 0x7fffu + ((c.u >> 16) & 1u)) >> 16);
}
// float -> order-preserving uint (ascending)
__device__ __forceinline__ unsigned ordkey(float f) {
    unsigned u = __float_as_uint(f);
    return u ^ ((u >> 31) ? 0xFFFFFFFFu : 0x80000000u);
}

// ---------------------------------------------------------------------------
// K0: kern (n, c*9+tap) -> kr fp32 [n][tap*64+c] (canonical-order refine walk)
//                        and kb bf16 [n][tap*64+c] (MFMA B operand source)
// ---------------------------------------------------------------------------
__global__ __launch_bounds__(256) void k_prep(const float* __restrict__ kern,
                                              float* __restrict__ kr,
                                              unsigned short* __restrict__ kb) {
    const int o = blockIdx.x * 256 + threadIdx.x;  // 1024*576 = 2304*256
    const int n = o / 576;
    const int r = o - n * 576;
    const int tap = r >> 6;
    const int c = r & 63;
    const float v = kern[n * 576 + c * 9 + tap];
    kr[o] = v;
    kb[o] = f2bf(v);
}

// ---------------------------------------------------------------------------
// K2: table[k][n][o] = sum_v conv_w[o, k*128+v] * values[n, v]  (unchanged)
// ---------------------------------------------------------------------------
__global__ __launch_bounds__(256) void k_table(const float* __restrict__ values,
                                               const float* __restrict__ conv_w,
                                               float* __restrict__ table) {
    __shared__ float wk[128][132];
    __shared__ float vals[16][128];

    const int t = threadIdx.x;
    const int k = blockIdx.x >> 6;
    const int n0 = (blockIdx.x & 63) * 16;

    {
        const int row = t >> 1;
        const int seg = (t & 1) * 64;
        const f4* src = (const f4*)(conv_w + row * 1024 + k * 128 + seg);
#pragma unroll
        for (int q = 0; q < 16; ++q) *(f4*)&wk[row][seg + q * 4] = src[q];
    }
    {
        const int r = t >> 4;
        const int col = (t & 15) * 8;
        const f4* src = (const f4*)(values + (n0 + r) * VDIM + col);
        *(f4*)&vals[r][col] = src[0];
        *(f4*)&vals[r][col + 4] = src[1];
    }
    __syncthreads();

    const int o = t & 127;
    const int ngrp = t >> 7;
    float acc[8];
#pragma unroll
    for (int r = 0; r < 8; ++r) acc[r] = 0.f;
    for (int v = 0; v < 128; ++v) {
        const float w = wk[o][v];
#pragma unroll
        for (int r = 0; r < 8; ++r) acc[r] = fmaf(w, vals[ngrp * 8 + r][v], acc[r]);
    }
#pragma unroll
    for (int r = 0; r < 8; ++r) {
        const int n = n0 + ngrp * 8 + r;
        table[(((k << 10) + n) << 7) + o] = acc[r];
    }
}

// ---------------------------------------------------------------------------
// K1: bf16 MFMA candidate GEMM + per-row top-10 per wave-owned n-sub-split.
// Block: 64 m, 4 waves; nt loops 4x256 n; wave w owns n = nt*256 + w*64 + c.
// MFMA 16x16x32 bf16: A[m=lane&15][k=(lane>>4)*8+j], B[n=lane&15][k=same],
// D col=lane&15 (n), row=(lane>>4)*4+reg (m).   Candidates only — exact
// ranking is restored by the canonical refine in K3.
// Output: packed keys (22-bit ordered value | 10-bit n) per sub-split.
// grid = MTOT/64 = 784 blocks, 256 threads.
// ---------------------------------------------------------------------------
__global__ __launch_bounds__(256, 3) void k_mfma_topk(const float* __restrict__ x,
                                                      const unsigned short* __restrict__ kb,
                                                      const float* __restrict__ bias,
                                                      unsigned* __restrict__ kws) {
    // smem: A bufs 2x[64][40] bf16 (5120 B each), B bufs 2x[256][40] bf16
    // (20480 B each). dist[64][65] f32 aliases B buf0 (barrier-separated).
    __shared__ char smem[51200];
    unsigned short* A0 = (unsigned short*)smem;
    unsigned short* A1 = (unsigned short*)(smem + 5120);
    unsigned short* B0 = (unsigned short*)(smem + 10240);
    unsigned short* B1 = (unsigned short*)(smem + 30720);
    float (*dist)[65] = (float (*)[65])(smem + 10240);

    const int t = threadIdx.x;
    const int w = t >> 6;           // wave = sub-split
    const int lane = t & 63;
    const int mfrag = lane & 15;
    const int kq = lane >> 4;

    const int m0 = blockIdx.x * 64;
    // A loader: thread = (ml = t&63, cg = t>>6): 8 channels per chunk
    const int ml = t & 63;
    const int cg = t >> 6;
    const int L = m0 + ml;
    const int b = L / 3136;
    const int hw = L - b * 3136;
    const int hh = hw / 56;
    const int wp = hw - hh * 56;
    const float* xb = x + b * (CH * 3136);
    // B loader: thread = (brow = t>>2, bseg = t&3), 4 row-passes
    const int brow = t >> 2;
    const int bseg = t & 3;

    float top_d[SK];
    unsigned top_k[SK];
#pragma unroll
    for (int j = 0; j < SK; ++j) { top_d[j] = 3.0e38f; top_k[j] = 0xFFFFFFFFu; }

    for (int nt = 0; nt < 4; ++nt) {
        const int n0 = nt * 256;

        f4 acc[4][4];
#pragma unroll
        for (int mi = 0; mi < 4; ++mi)
#pragma unroll
            for (int ni = 0; ni < 4; ++ni) acc[mi][ni] = (f4)0.f;

        // ---- stage chunk 0 into buf0 ----
        {
            const int tap = 0, c0 = 0;
            const int hy = hh + tap / 3 - 1;        // tap 0 -> dh 0, dw 0
            const int wx = wp + tap % 3 - 1;
            const bool inb = ((unsigned)hy < 56u && (unsigned)wx < 56u);
            const float* xp = xb + (c0 + cg * 8) * 3136 + hy * 56 + wx;
            unsigned short tmp[8];
#pragma unroll
            for (int j = 0; j < 8; ++j) tmp[j] = inb ? f2bf(xp[j * 3136]) : (unsigned short)0;
            *(i4*)&A0[ml * 40 + cg * 8] = *(i4*)tmp;
#pragma unroll
            for (int p = 0; p < 4; ++p) {
                const int nn = p * 64 + brow;
                const i4 v = *(const i4*)(kb + (n0 + nn) * KTOT + 0 * 32 + bseg * 8);
                *(i4*)&B0[nn * 40 + bseg * 8] = v;
            }
        }
        __syncthreads();

#pragma unroll 1
        for (int ch = 0; ch < 18; ++ch) {
            unsigned short* Ac = (ch & 1) ? A1 : A0;
            unsigned short* Bc = (ch & 1) ? B1 : B0;
            if (ch < 17) {
                const int chn = ch + 1;
                unsigned short* An = (chn & 1) ? A1 : A0;
                unsigned short* Bn = (chn & 1) ? B1 : B0;
                const int tap = chn >> 1;
                const int c0 = (chn & 1) * 32;
                const int dh = tap / 3;
                const int dw = tap - dh * 3;
                const int hy = hh + dh - 1;
                const int wx = wp + dw - 1;
                const bool inb = ((unsigned)hy < 56u && (unsigned)wx < 56u);
                const float* xp = xb + (c0 + cg * 8) * 3136 + hy * 56 + wx;
                unsigned short tmp[8];
#pragma unroll
                for (int j = 0; j < 8; ++j) tmp[j] = inb ? f2bf(xp[j * 3136]) : (unsigned short)0;
                *(i4*)&An[ml * 40 + cg * 8] = *(i4*)tmp;
#pragma unroll
                for (int p = 0; p < 4; ++p) {
                    const int nn = p * 64 + brow;
                    const i4 v = *(const i4*)(kb + (n0 + nn) * KTOT + chn * 32 + bseg * 8);
                    *(i4*)&Bn[nn * 40 + bseg * 8] = v;
                }
            }
            // compute on current buffer
            bf16x8 af[4], bfr[4];
#pragma unroll
            for (int mi = 0; mi < 4; ++mi)
                af[mi] = *(const bf16x8*)&Ac[(mi * 16 + mfrag) * 40 + kq * 8];
#pragma unroll
            for (int ni = 0; ni < 4; ++ni)
                bfr[ni] = *(const bf16x8*)&Bc[(w * 64 + ni * 16 + mfrag) * 40 + kq * 8];
#pragma unroll
            for (int mi = 0; mi < 4; ++mi)
#pragma unroll
                for (int ni = 0; ni < 4; ++ni)
                    acc[mi][ni] = __builtin_amdgcn_mfma_f32_16x16x32_bf16(
                        af[mi], bfr[ni], acc[mi][ni], 0, 0, 0);
            __syncthreads();
        }

        // bias for this wave's n-columns
        float bv[4];
#pragma unroll
        for (int ni = 0; ni < 4; ++ni)
            bv[ni] = bias[n0 + w * 64 + ni * 16 + mfrag];

        // wave-serialized: write own 64x64 quarter to dist, scan rows
#pragma unroll 1
        for (int q = 0; q < 4; ++q) {
            if (w == q) {
#pragma unroll
                for (int mi = 0; mi < 4; ++mi)
#pragma unroll
                    for (int ni = 0; ni < 4; ++ni)
#pragma unroll
                        for (int r = 0; r < 4; ++r)
                            dist[mi * 16 + kq * 4 + r][ni * 16 + mfrag] = acc[mi][ni][r] + bv[ni];
                // scan own rows (lane = m-row); ascending c = ascending n
                const int nb = (n0 + q * 64);
                float tlast = top_d[SK - 1];
#pragma unroll 8
                for (int c = 0; c < 64; ++c) {
                    const float v = dist[lane][c];
                    if (v < tlast) {
                        const unsigned key = (ordkey(v) & 0xFFFFFC00u) | (unsigned)(nb + c);
                        top_d[SK - 1] = v; top_k[SK - 1] = key;
#pragma unroll
                        for (int j = SK - 1; j >= 1; --j) {
                            if (top_d[j] < top_d[j - 1]) {
                                const float a = top_d[j]; top_d[j] = top_d[j - 1]; top_d[j - 1] = a;
                                const unsigned kk = top_k[j]; top_k[j] = top_k[j - 1]; top_k[j - 1] = kk;
                            }
                        }
                        tlast = top_d[SK - 1];
                    }
                }
            }
            __syncthreads();
        }
    }

#pragma unroll
    for (int j = 0; j < SK; ++j)
        kws[(w * SK + j) * MTOT + m0 + lane] = top_k[j];
}

// ---------------------------------------------------------------------------
// K3: merge 4x10 packed candidates -> top-16 pool (uint key order), refine
// each candidate with the CANONICAL chain (single fp32 acc, fmaf, tap-major
// c-innermost over kr; oob taps skipped — fmaf(0,k,a)==a exactly), + bias,
// stable lex (fp32,idx) top-8, gather table rows, write out.
// grid = MTOT/16 = 3136 blocks, 256 threads (16 locs x 16 cands).
// ---------------------------------------------------------------------------
__global__ __launch_bounds__(256) void k_refine_out(const float* __restrict__ x,
                                                    const float* __restrict__ kr,
                                                    const float* __restrict__ bias,
                                                    const unsigned* __restrict__ kws,
                                                    const float* __restrict__ table,
                                                    const float* __restrict__ conv_b,
                                                    float* __restrict__ out) {
    __shared__ int   ids[16][POOL];
    __shared__ float dd[16][POOL];
    __shared__ int   id8s[16][TOPK];

    const int t = threadIdx.x;
    const int l0 = blockIdx.x * 16;
    const int b = l0 / 3136;           // 16 | 3136 -> uniform
    const float* xb = x + b * (CH * 3136);

    // 1) per-location merge of 40 packed keys -> top-16 pool
    if (t < 16) {
        const int gl = l0 + t;
        unsigned tk[POOL];
#pragma unroll
        for (int r = 0; r < POOL; ++r) tk[r] = 0xFFFFFFFFu;
#pragma unroll
        for (int s = 0; s < NSUB; ++s)
#pragma unroll
            for (int j = 0; j < SK; ++j) {
                const unsigned k = kws[(s * SK + j) * MTOT + gl];
                if (k < tk[POOL - 1]) {
                    tk[POOL - 1] = k;
#pragma unroll
                    for (int r = POOL - 1; r >= 1; --r) {
                        if (tk[r] < tk[r - 1]) { const unsigned a = tk[r]; tk[r] = tk[r - 1]; tk[r - 1] = a; }
                    }
                }
            }
#pragma unroll
        for (int r = 0; r < POOL; ++r) ids[t][r] = (int)(tk[r] & 1023u);
    }
    __syncthreads();

    // 2) canonical refine: thread (loc = t&15, cand = t>>4)
    {
        const int loc = t & 15;
        const int cand = t >> 4;
        const int gl = l0 + loc;
        const int hw = gl - b * 3136;
        const int hh = hw / 56;
        const int wp = hw - hh * 56;
        const int cd = ids[loc][cand];
        const float* kp = kr + cd * KTOT;
        float a = 0.f;
#pragma unroll 1
        for (int tap = 0; tap < 9; ++tap) {
            const int dh = tap / 3;
            const int dw = tap - dh * 3;
            const int hy = hh + dh - 1;
            const int wx = wp + dw - 1;
            if ((unsigned)hy < 56u && (unsigned)wx < 56u) {
                const float* xp = xb + hy * 56 + wx;
                const float* kt = kp + tap * 64;
#pragma unroll 8
                for (int c = 0; c < 64; ++c)
                    a = fmaf(xp[c * 3136], kt[c], a);
            }
        }
        dd[loc][cand] = a + bias[cd];
    }
    __syncthreads();

    // 3) stable lex (fp32 value, index) top-8 of 16
    if (t < 16) {
        float td[TOPK]; int ti[TOPK];
#pragma unroll
        for (int j = 0; j < TOPK; ++j) { td[j] = 3.0e38f; ti[j] = 0x7fffffff; }
#pragma unroll
        for (int j = 0; j < POOL; ++j) {
            const float v = dd[t][j];
            const int ii = ids[t][j];
            if (v < td[TOPK - 1] || (v == td[TOPK - 1] && ii < ti[TOPK - 1])) {
                td[TOPK - 1] = v; ti[TOPK - 1] = ii;
#pragma unroll
                for (int q = TOPK - 1; q >= 1; --q) {
                    if (td[q] < td[q - 1] || (td[q] == td[q - 1] && ti[q] < ti[q - 1])) {
                        const float a = td[q]; td[q] = td[q - 1]; td[q - 1] = a;
                        const int bq = ti[q]; ti[q] = ti[q - 1]; ti[q - 1] = bq;
                    }
                }
            }
        }
#pragma unroll
        for (int j = 0; j < TOPK; ++j) id8s[t][j] = ti[j];
    }
    __syncthreads();

    // 4) gather + out: thread (loc = t&15, og = t>>4): channels og*8..+7
    {
        const int loc = t & 15;
        const int og = t >> 4;
        const int gl = l0 + loc;
        const int hw = gl - b * 3136;
        const int o0 = og * 8;
        int idx[TOPK];
#pragma unroll
        for (int j = 0; j < TOPK; ++j) idx[j] = id8s[loc][j];
        f4 a0 = *(const f4*)&conv_b[o0];
        f4 a1 = *(const f4*)&conv_b[o0 + 4];
#pragma unroll
        for (int k = 0; k < TOPK; ++k) {
            const float* row = table + (((k << 10) + idx[k]) << 7) + o0;
            a0 += *(const f4*)&row[0];
            a1 += *(const f4*)&row[4];
        }
        float* ob = out + b * (VDIM * 3136) + hw;
#pragma unroll
        for (int e = 0; e < 4; ++e) {
            ob[(o0 + e) * 3136] = a0[e];
            ob[(o0 + 4 + e) * 3136] = a1[e];
        }
    }
}

// ---------------------------------------------------------------------------
// ws layout (float slots): kr 589824 | kb 294912 (bf16) | table 1048576 |
// kws 2007040  -> total 3,940,352 floats ~= 15.8 MB
// ---------------------------------------------------------------------------
extern "C" void kernel_launch(void* const* d_in, const int* in_sizes, int n_in,
                              void* d_out, int out_size, void* d_ws, size_t ws_size,
                              hipStream_t stream) {
    const float* x      = (const float*)d_in[0];
    const float* kern   = (const float*)d_in[1];
    const float* bias   = (const float*)d_in[2];
    const float* values = (const float*)d_in[3];
    const float* conv_w = (const float*)d_in[4];
    const float* conv_b = (const float*)d_in[5];
    float* out = (float*)d_out;

    float* kr = (float*)d_ws;                          // 1024*576 f32
    unsigned short* kb = (unsigned short*)(kr + NCENT * KTOT);   // 1024*576 bf16
    float* table = (float*)(kb + NCENT * KTOT);        // 8*1024*128 f32
    unsigned* kws = (unsigned*)(table + 8 * NCENT * VDIM);       // 4*10*50176 u32

    k_prep<<<dim3(NCENT * KTOT / 256), dim3(256), 0, stream>>>(kern, kr, kb);
    k_table<<<dim3(8 * 64), dim3(256), 0, stream>>>(values, conv_w, table);
    k_mfma_topk<<<dim3(MTOT / 64), dim3(256), 0, stream>>>(x, kb, bias, kws);
    k_refine_out<<<dim3(MTOT / 16), dim3(256), 0, stream>>>(x, kr, bias, kws, table, conv_b, out);
}

// Round 12
// 871.193 us; speedup vs baseline: 8.2479x; 1.1352x over previous
//
#include <hip/hip_runtime.h>

// Problem constants
#define BATCH   16
#define CH      64
#define NCENT   1024
#define KTOT    576      // 64 ch * 9 taps
#define MTOT    50176    // B*H*W
#define VDIM    128
#define TOPK    8
#define SK      10       // bf16 candidates kept per 256-n sub-split
#define POOL    16       // merged candidates refined canonically

typedef float f4 __attribute__((ext_vector_type(4)));
typedef short bf16x8 __attribute__((ext_vector_type(8)));
typedef int i4 __attribute__((ext_vector_type(4)));

__device__ __forceinline__ unsigned short f2bf(float f) {
    union { float f; unsigned u; } c; c.f = f;
    return (unsigned short)((c.u + 0x7fffu + ((c.u >> 16) & 1u)) >> 16);
}
__device__ __forceinline__ unsigned ordkey(float f) {
    unsigned u = __float_as_uint(f);
    return u ^ ((u >> 31) ? 0xFFFFFFFFu : 0x80000000u);
}

// ---------------------------------------------------------------------------
// K0: kern (n, c*9+tap) -> kr fp32 [n][tap*64+c] (canonical refine walk)
//                        and kb bf16 [n][tap*64+c] (MFMA B operand)
// ---------------------------------------------------------------------------
__global__ __launch_bounds__(256) void k_prep(const float* __restrict__ kern,
                                              float* __restrict__ kr,
                                              unsigned short* __restrict__ kb) {
    const int o = blockIdx.x * 256 + threadIdx.x;  // 1024*576 = 2304*256
    const int n = o / 576;
    const int r = o - n * 576;
    const int tap = r >> 6;
    const int c = r & 63;
    const float v = kern[n * 576 + c * 9 + tap];
    kr[o] = v;
    kb[o] = f2bf(v);
}

// ---------------------------------------------------------------------------
// K2: table[k][n][o] = sum_v conv_w[o, k*128+v] * values[n, v]  (unchanged)
// ---------------------------------------------------------------------------
__global__ __launch_bounds__(256) void k_table(const float* __restrict__ values,
                                               const float* __restrict__ conv_w,
                                               float* __restrict__ table) {
    __shared__ float wk[128][132];
    __shared__ float vals[16][128];

    const int t = threadIdx.x;
    const int k = blockIdx.x >> 6;
    const int n0 = (blockIdx.x & 63) * 16;

    {
        const int row = t >> 1;
        const int seg = (t & 1) * 64;
        const f4* src = (const f4*)(conv_w + row * 1024 + k * 128 + seg);
#pragma unroll
        for (int q = 0; q < 16; ++q) *(f4*)&wk[row][seg + q * 4] = src[q];
    }
    {
        const int r = t >> 4;
        const int col = (t & 15) * 8;
        const f4* src = (const f4*)(values + (n0 + r) * VDIM + col);
        *(f4*)&vals[r][col] = src[0];
        *(f4*)&vals[r][col + 4] = src[1];
    }
    __syncthreads();

    const int o = t & 127;
    const int ngrp = t >> 7;
    float acc[8];
#pragma unroll
    for (int r = 0; r < 8; ++r) acc[r] = 0.f;
    for (int v = 0; v < 128; ++v) {
        const float w = wk[o][v];
#pragma unroll
        for (int r = 0; r < 8; ++r) acc[r] = fmaf(w, vals[ngrp * 8 + r][v], acc[r]);
    }
#pragma unroll
    for (int r = 0; r < 8; ++r) {
        const int n = n0 + ngrp * 8 + r;
        table[(((k << 10) + n) << 7) + o] = acc[r];
    }
}

// ---------------------------------------------------------------------------
// K1 (fused): bf16 MFMA candidate GEMM over all 1024 n for 64 locations,
// PARALLEL per-sub-split top-10 scan (thread = (row, quarter), no wave
// serialization), in-block merge -> pool-16, canonical fp32 refine (exact
// reference chain: tap-major, c-innermost, single fmaf accumulator, one
// +bias), lex (fp32,idx) top-8, table gather, output.
// grid = MTOT/64 = 784 blocks, 256 threads.
// ---------------------------------------------------------------------------
__global__ __launch_bounds__(256, 2) void k_fused(const float* __restrict__ x,
                                                  const unsigned short* __restrict__ kb,
                                                  const float* __restrict__ kr,
                                                  const float* __restrict__ bias,
                                                  const float* __restrict__ table,
                                                  const float* __restrict__ conv_b,
                                                  float* __restrict__ out) {
    // Staging: A 2x[64][40]bf16 (5120 B), B 2x[256][40]bf16 (20480 B) = 51200.
    // dist[64][257] f32 (65792 B) aliases everything (phase-separated).
    // Refine-phase structures also alias dist (all dead by then):
    //   keys u32[64][41] @0 (10496) | ids i32[64*16] @10496 (4096) |
    //   dd f32[64*16] @14592 (4096) | id8 i32[64*8] @18688 (2048) |
    //   xl f32[64*69] @20736 (17664)
    __shared__ char smem[65792];
    unsigned short* A0 = (unsigned short*)smem;
    unsigned short* A1 = (unsigned short*)(smem + 5120);
    unsigned short* B0 = (unsigned short*)(smem + 10240);
    unsigned short* B1 = (unsigned short*)(smem + 30720);
    float (*dist)[257] = (float (*)[257])smem;
    unsigned* keys = (unsigned*)smem;                 // [64][41]
    int*      ids  = (int*)(smem + 10496);            // [64][16]
    float*    dd   = (float*)(smem + 14592);          // [64][16]
    int*      id8  = (int*)(smem + 18688);            // [64][8]
    float*    xl   = (float*)(smem + 20736);          // [64 loc][69]

    const int t = threadIdx.x;
    const int w = t >> 6;           // wave
    const int lane = t & 63;
    const int mfrag = lane & 15;
    const int kq = lane >> 4;

    const int m0 = blockIdx.x * 64;
    // per-thread location (used by A loader, xl loader, refine, output)
    const int ml = t & 63;
    const int cg = t >> 6;
    const int L = m0 + ml;
    const int b = L / 3136;         // uniform per block (64 | 3136)
    const int hw = L - b * 3136;
    const int hh = hw / 56;
    const int wp = hw - hh * 56;
    const float* xb = x + b * (CH * 3136);
    // B loader
    const int brow = t >> 2;
    const int bseg = t & 3;

    // sub-split scan state: thread (sr = ml, sq = cg) owns rows sr,
    // n in {nt*256 + sq*64 + c}
    float top_d[SK];
    unsigned top_k[SK];
#pragma unroll
    for (int j = 0; j < SK; ++j) { top_d[j] = 3.0e38f; top_k[j] = 0xFFFFFFFFu; }

    for (int nt = 0; nt < 4; ++nt) {
        const int n0 = nt * 256;

        f4 acc[4][4];
#pragma unroll
        for (int mi = 0; mi < 4; ++mi)
#pragma unroll
            for (int ni = 0; ni < 4; ++ni) acc[mi][ni] = (f4)0.f;

        __syncthreads();  // dist-region reads of previous nt's scan done

        // ---- stage chunk 0 into buf0 ----
        {
            const int hy = hh - 1;   // tap 0 -> dh 0, dw 0
            const int wx = wp - 1;
            const bool inb = ((unsigned)hy < 56u && (unsigned)wx < 56u);
            const float* xp = xb + (cg * 8) * 3136 + hy * 56 + wx;
            unsigned short tmp[8];
#pragma unroll
            for (int j = 0; j < 8; ++j) tmp[j] = inb ? f2bf(xp[j * 3136]) : (unsigned short)0;
            *(i4*)&A0[ml * 40 + cg * 8] = *(i4*)tmp;
#pragma unroll
            for (int p = 0; p < 4; ++p) {
                const int nn = p * 64 + brow;
                const i4 v = *(const i4*)(kb + (n0 + nn) * KTOT + bseg * 8);
                *(i4*)&B0[nn * 40 + bseg * 8] = v;
            }
        }
        __syncthreads();

#pragma unroll 1
        for (int ch = 0; ch < 18; ++ch) {
            unsigned short* Ac = (ch & 1) ? A1 : A0;
            unsigned short* Bc = (ch & 1) ? B1 : B0;
            if (ch < 17) {
                const int chn = ch + 1;
                unsigned short* An = (chn & 1) ? A1 : A0;
                unsigned short* Bn = (chn & 1) ? B1 : B0;
                const int tap = chn >> 1;
                const int c0 = (chn & 1) * 32;
                const int dh = tap / 3;
                const int dw = tap - dh * 3;
                const int hy = hh + dh - 1;
                const int wx = wp + dw - 1;
                const bool inb = ((unsigned)hy < 56u && (unsigned)wx < 56u);
                const float* xp = xb + (c0 + cg * 8) * 3136 + hy * 56 + wx;
                unsigned short tmp[8];
#pragma unroll
                for (int j = 0; j < 8; ++j) tmp[j] = inb ? f2bf(xp[j * 3136]) : (unsigned short)0;
                *(i4*)&An[ml * 40 + cg * 8] = *(i4*)tmp;
#pragma unroll
                for (int p = 0; p < 4; ++p) {
                    const int nn = p * 64 + brow;
                    const i4 v = *(const i4*)(kb + (n0 + nn) * KTOT + chn * 32 + bseg * 8);
                    *(i4*)&Bn[nn * 40 + bseg * 8] = v;
                }
            }
            bf16x8 af[4], bfr[4];
#pragma unroll
            for (int mi = 0; mi < 4; ++mi)
                af[mi] = *(const bf16x8*)&Ac[(mi * 16 + mfrag) * 40 + kq * 8];
#pragma unroll
            for (int ni = 0; ni < 4; ++ni)
                bfr[ni] = *(const bf16x8*)&Bc[(w * 64 + ni * 16 + mfrag) * 40 + kq * 8];
#pragma unroll
            for (int mi = 0; mi < 4; ++mi)
#pragma unroll
                for (int ni = 0; ni < 4; ++ni)
                    acc[mi][ni] = __builtin_amdgcn_mfma_f32_16x16x32_bf16(
                        af[mi], bfr[ni], acc[mi][ni], 0, 0, 0);
            __syncthreads();
        }

        // all MFMA reads done -> write dist (+bias), all 4 waves concurrent
        {
            float bv[4];
#pragma unroll
            for (int ni = 0; ni < 4; ++ni)
                bv[ni] = bias[n0 + w * 64 + ni * 16 + mfrag];
#pragma unroll
            for (int mi = 0; mi < 4; ++mi)
#pragma unroll
                for (int ni = 0; ni < 4; ++ni)
#pragma unroll
                    for (int r = 0; r < 4; ++r)
                        dist[mi * 16 + kq * 4 + r][w * 64 + ni * 16 + mfrag] =
                            acc[mi][ni][r] + bv[ni];
        }
        __syncthreads();

        // parallel scan: thread (ml, cg) scans row ml, cols cg*64..+63
        {
            const int nb = n0 + cg * 64;
            float tlast = top_d[SK - 1];
#pragma unroll 8
            for (int c = 0; c < 64; ++c) {
                const float v = dist[ml][cg * 64 + c];
                if (v < tlast) {
                    const unsigned key = (ordkey(v) & 0xFFFFFC00u) | (unsigned)(nb + c);
                    top_d[SK - 1] = v; top_k[SK - 1] = key;
#pragma unroll
                    for (int j = SK - 1; j >= 1; --j) {
                        if (top_d[j] < top_d[j - 1]) {
                            const float a = top_d[j]; top_d[j] = top_d[j - 1]; top_d[j - 1] = a;
                            const unsigned kk = top_k[j]; top_k[j] = top_k[j - 1]; top_k[j - 1] = kk;
                        }
                    }
                    tlast = top_d[SK - 1];
                }
            }
        }
    }
    __syncthreads();  // scans done; dist region dead -> keys may overwrite

    // write per-sub-split candidate keys
#pragma unroll
    for (int j = 0; j < SK; ++j) keys[ml * 41 + cg * SK + j] = top_k[j];
    __syncthreads();

    // merge 4x10 -> pool-16 (uint key order = (trunc value, n) lex)
    if (t < 64) {
        unsigned tk[POOL];
#pragma unroll
        for (int r = 0; r < POOL; ++r) tk[r] = 0xFFFFFFFFu;
#pragma unroll
        for (int s = 0; s < 4; ++s)
#pragma unroll
            for (int j = 0; j < SK; ++j) {
                const unsigned k = keys[t * 41 + s * SK + j];
                if (k < tk[POOL - 1]) {
                    tk[POOL - 1] = k;
#pragma unroll
                    for (int r = POOL - 1; r >= 1; --r) {
                        if (tk[r] < tk[r - 1]) { const unsigned a = tk[r]; tk[r] = tk[r - 1]; tk[r - 1] = a; }
                    }
                }
            }
#pragma unroll
        for (int r = 0; r < POOL; ++r) ids[t * POOL + r] = (int)(tk[r] & 1023u);
    }
    __syncthreads();

    // canonical refine: thread (ml, cg) runs 4 chains (cands cg*4+0..3)
    int cd[4];
    const float* kp[4];
#pragma unroll
    for (int j = 0; j < 4; ++j) {
        cd[j] = ids[ml * POOL + cg * 4 + j];
        kp[j] = kr + cd[j] * KTOT;
    }
    float a0 = 0.f, a1 = 0.f, a2 = 0.f, a3 = 0.f;

#pragma unroll 1
    for (int tap = 0; tap < 9; ++tap) {
        const int dh = tap / 3;
        const int dw = tap - dh * 3;
        const int hy = hh + dh - 1;
        const int wx = wp + dw - 1;
        const bool inb = ((unsigned)hy < 56u && (unsigned)wx < 56u);
        __syncthreads();  // previous tap's xl reads done
        // stage x fp32 for this tap: writer (ml loc, cg -> 16 channels)
#pragma unroll
        for (int i = 0; i < 16; ++i) {
            float v = 0.f;
            if (inb) v = xb[(cg * 16 + i) * 3136 + hy * 56 + wx];
            xl[ml * 69 + cg * 16 + i] = v;
        }
        __syncthreads();
        // chains advance through this tap, c ascending (canonical order);
        // OOB taps contribute fmaf(0, k, a) == a (bit-exact skip)
        const int tb = tap * 64;
#pragma unroll 4
        for (int c4 = 0; c4 < 16; ++c4) {
            const f4 k0 = *(const f4*)&kp[0][tb + c4 * 4];
            const f4 k1 = *(const f4*)&kp[1][tb + c4 * 4];
            const f4 k2 = *(const f4*)&kp[2][tb + c4 * 4];
            const f4 k3 = *(const f4*)&kp[3][tb + c4 * 4];
#pragma unroll
            for (int e = 0; e < 4; ++e) {
                const float xv = xl[ml * 69 + c4 * 4 + e];
                a0 = fmaf(xv, k0[e], a0);
                a1 = fmaf(xv, k1[e], a1);
                a2 = fmaf(xv, k2[e], a2);
                a3 = fmaf(xv, k3[e], a3);
            }
        }
    }
    dd[ml * POOL + cg * 4 + 0] = a0 + bias[cd[0]];
    dd[ml * POOL + cg * 4 + 1] = a1 + bias[cd[1]];
    dd[ml * POOL + cg * 4 + 2] = a2 + bias[cd[2]];
    dd[ml * POOL + cg * 4 + 3] = a3 + bias[cd[3]];
    __syncthreads();

    // stable lex (fp32 value, index) top-8 of 16
    if (t < 64) {
        float td[TOPK]; int ti[TOPK];
#pragma unroll
        for (int j = 0; j < TOPK; ++j) { td[j] = 3.0e38f; ti[j] = 0x7fffffff; }
#pragma unroll
        for (int j = 0; j < POOL; ++j) {
            const float v = dd[t * POOL + j];
            const int ii = ids[t * POOL + j];
            if (v < td[TOPK - 1] || (v == td[TOPK - 1] && ii < ti[TOPK - 1])) {
                td[TOPK - 1] = v; ti[TOPK - 1] = ii;
#pragma unroll
                for (int q = TOPK - 1; q >= 1; --q) {
                    if (td[q] < td[q - 1] || (td[q] == td[q - 1] && ti[q] < ti[q - 1])) {
                        const float a = td[q]; td[q] = td[q - 1]; td[q - 1] = a;
                        const int bq = ti[q]; ti[q] = ti[q - 1]; ti[q - 1] = bq;
                    }
                }
            }
        }
#pragma unroll
        for (int j = 0; j < TOPK; ++j) id8[t * TOPK + j] = ti[j];
    }
    __syncthreads();

    // output: thread (ml, cg) handles o-channels cg*32..+31
    {
        const int o0 = cg * 32;
        int idx[TOPK];
#pragma unroll
        for (int j = 0; j < TOPK; ++j) idx[j] = id8[ml * TOPK + j];
        f4 acc8[8];
#pragma unroll
        for (int q = 0; q < 8; ++q) acc8[q] = *(const f4*)&conv_b[o0 + q * 4];
#pragma unroll
        for (int k = 0; k < TOPK; ++k) {
            const float* row = table + (((k << 10) + idx[k]) << 7) + o0;
#pragma unroll
            for (int q = 0; q < 8; ++q) acc8[q] += *(const f4*)&row[q * 4];
        }
        float* ob = out + b * (VDIM * 3136) + hw;
#pragma unroll
        for (int q = 0; q < 8; ++q)
#pragma unroll
            for (int e = 0; e < 4; ++e)
                ob[(o0 + q * 4 + e) * 3136] = acc8[q][e];
    }
}

// ---------------------------------------------------------------------------
// ws layout: kr 576*1024 f32 | kb 576*1024 bf16 | table 8*1024*128 f32 ~ 7.7MB
// ---------------------------------------------------------------------------
extern "C" void kernel_launch(void* const* d_in, const int* in_sizes, int n_in,
                              void* d_out, int out_size, void* d_ws, size_t ws_size,
                              hipStream_t stream) {
    const float* x      = (const float*)d_in[0];
    const float* kern   = (const float*)d_in[1];
    const float* bias   = (const float*)d_in[2];
    const float* values = (const float*)d_in[3];
    const float* conv_w = (const float*)d_in[4];
    const float* conv_b = (const float*)d_in[5];
    float* out = (float*)d_out;

    float* kr = (float*)d_ws;                                     // f32
    unsigned short* kb = (unsigned short*)(kr + NCENT * KTOT);    // bf16
    float* table = (float*)(kb + NCENT * KTOT);                   // f32

    k_prep<<<dim3(NCENT * KTOT / 256), dim3(256), 0, stream>>>(kern, kr, kb);
    k_table<<<dim3(8 * 64), dim3(256), 0, stream>>>(values, conv_w, table);
    k_fused<<<dim3(MTOT / 64), dim3(256), 0, stream>>>(x, kb, kr, bias, table, conv_b, out);
}